// Round 8
// baseline (212.828 us; speedup 1.0000x reference)
//
#include <hip/hip_runtime.h>
#include <hip/hip_bf16.h>
#include <stdint.h>

#define NN 4096      // nodes
#define KD 512       // input dim of both GEMMs (512 = IN_DIM = HID*HEADS)
#define LOG2E 1.4426950408889634f

typedef __attribute__((ext_vector_type(8))) short short8;
typedef __attribute__((ext_vector_type(4))) float f32x4;

__device__ __forceinline__ float lrelu(float x) { return fmaxf(x, 0.2f * x); }

__device__ __forceinline__ unsigned short f2bf(float f) {
    uint32_t u = __float_as_uint(f);
    u += 0x7fff + ((u >> 16) & 1);           // RNE
    return (unsigned short)(u >> 16);
}

// 2^x via hardware transcendental (scores are pre-scaled by log2e)
__device__ __forceinline__ float exp2_fast(float x) {
    float r; asm("v_exp_f32 %0, %1" : "=v"(r) : "v"(x)); return r;
}

// pack 2 f32 -> 2 bf16 (RNE), lo -> [15:0], hi -> [31:16]
__device__ __forceinline__ uint32_t cvt_pk_bf16(float lo, float hi) {
    uint32_t r; asm("v_cvt_pk_bf16_f32 %0, %1, %2" : "=v"(r) : "v"(lo), "v"(hi)); return r;
}

// async global->LDS, 16B per lane; lds ptr must be wave-uniform base
__device__ __forceinline__ void glds16(const void* g, void* l) {
    __builtin_amdgcn_global_load_lds(
        (const __attribute__((address_space(1))) uint32_t*)g,
        (__attribute__((address_space(3))) uint32_t*)l, 16, 0, 0);
}

// ---------------- bitmask: g[N][N] int32 -> bm[N][64] uint64 ----------------
__global__ void k_bitmask(const int* __restrict__ g, uint64_t* __restrict__ bm) {
    int wave = threadIdx.x >> 6;
    int lane = threadIdx.x & 63;
    int row = blockIdx.x * 4 + wave;
    const int* grow = g + (size_t)row * NN;
    #pragma unroll 4
    for (int w = 0; w < 64; ++w) {
        int v = grow[w * 64 + lane];
        unsigned long long m = __ballot(v > 0);
        if (lane == 0) bm[(size_t)row * 64 + w] = m;
    }
}

// ---------------- cast f32 -> bf16 (vectorized) ----------------
__global__ void k_cast(const float* __restrict__ x, unsigned short* __restrict__ y, int n4) {
    int i = blockIdx.x * 256 + threadIdx.x;
    if (i < n4) {
        float4 v = ((const float4*)x)[i];
        uint2 o;
        o.x = (uint32_t)f2bf(v.x) | ((uint32_t)f2bf(v.y) << 16);
        o.y = (uint32_t)f2bf(v.z) | ((uint32_t)f2bf(v.w) << 16);
        ((uint2*)y)[i] = o;
    }
}

// ---------------- generic transpose+cast: src f32 [b][R][C] -> dst bf16 [b][C][R] ----------------
__global__ __launch_bounds__(256)
void k_tc(const float* __restrict__ src, unsigned short* __restrict__ dst, int R, int C) {
    __shared__ float tile[64][65];
    int b = blockIdx.z;
    int r0 = blockIdx.x * 64, c0 = blockIdx.y * 64;
    src += (size_t)b * R * C;
    dst += (size_t)b * C * R;
    int t = threadIdx.x;
    #pragma unroll
    for (int s = 0; s < 16; ++s) {
        int idx = t + s * 256;
        int r = idx >> 6, c = idx & 63;
        tile[r][c] = src[(size_t)(r0 + r) * C + c0 + c];
    }
    __syncthreads();
    #pragma unroll
    for (int s = 0; s < 16; ++s) {
        int idx = t + s * 256;
        int r = idx >> 6, c = idx & 63;
        dst[(size_t)(c0 + r) * R + r0 + c] = f2bf(tile[c][r]);
    }
}

// ---------------- fused MFMA GEMM: Wh = A @ W, epilogue writes j-TILED WhT bf16 ----
// A bf16 [NN][512], WT bf16 [nh][F][512]. BM=32, BK=64, 8 waves (2row x 4col).
// WhT layout: [h][j/128][F][128] -- each 128-j tile is a CONTIGUOUS F*128*2B block,
// so the aggregation kernel's glds16 staging is sector-perfect coalesced (the [F][NN]
// layout forced a 16-row scatter-gather per glds16 -- the R2..R7 latency culprit).
// s1/s2/smax are written PRE-SCALED by log2(e).
template <int F>
__global__ __launch_bounds__(512)
void k_gemm_fused(const unsigned short* __restrict__ Abf, const unsigned short* __restrict__ WT,
                  const float* __restrict__ avec,
                  unsigned short* __restrict__ WhT, float* __restrict__ s1g,
                  float* __restrict__ s2g, unsigned int* __restrict__ smaxKey) {
    constexpr int BM = 32, BK = 64;
    constexpr int NCF = F / 64;
    __shared__ unsigned short a_lds[2][BM * BK];
    __shared__ unsigned short b_lds[2][F * BK];
    __shared__ unsigned short t_lds[F * 40];
    __shared__ float sred[BM][2];
    int t = threadIdx.x, lane = t & 63, w = t >> 6;
    int h = blockIdx.y;
    int i0 = blockIdx.x * BM;
    const unsigned short* WTh = WT + (size_t)h * F * KD;
    int r0 = (w >> 2) * 16, c0 = (w & 3) * (F / 4);
    int krow = lane & 15, kgrp = lane >> 4;
    if (t < BM) { sred[t][0] = 0.f; sred[t][1] = 0.f; }
    f32x4 acc[NCF];
    #pragma unroll
    for (int cf = 0; cf < NCF; ++cf) acc[cf] = (f32x4){0.f, 0.f, 0.f, 0.f};

    auto stage = [&](int buf, int kt) {
        int k0 = kt * BK;
        if (w < 4) {            // A tile: 256 chunks
            int c = w * 64 + lane;
            int row = c >> 3, slot = c & 7;
            glds16(Abf + (size_t)(i0 + row) * KD + k0 + ((slot ^ (row & 7)) * 8),
                   &a_lds[buf][(w * 64) * 8]);
        }
        #pragma unroll
        for (int s = 0; s < F / 64; ++s) {   // B tile: 8F chunks
            int c = w * F + s * 64 + lane;
            int row = c >> 3, slot = c & 7;
            glds16(WTh + (size_t)row * KD + k0 + ((slot ^ (row & 7)) * 8),
                   &b_lds[buf][(w * F + s * 64) * 8]);
        }
    };

    stage(0, 0);
    __syncthreads();
    int cur = 0;
    for (int kt = 0; kt < KD / BK; ++kt) {
        int nxt = cur ^ 1;
        if (kt + 1 < KD / BK) stage(nxt, kt + 1);
        #pragma unroll
        for (int ks = 0; ks < 2; ++ks) {
            int koff = ks * 32 + kgrp * 8;
            int arow = r0 + krow;
            short8 av = *(const short8*)((const char*)&a_lds[cur][arow * BK] +
                                         ((koff * 2) ^ ((arow & 7) << 4)));
            #pragma unroll
            for (int cf = 0; cf < NCF; ++cf) {
                int brow = c0 + cf * 16 + krow;
                short8 bv = *(const short8*)((const char*)&b_lds[cur][brow * BK] +
                                             ((koff * 2) ^ ((brow & 7) << 4)));
                acc[cf] = __builtin_amdgcn_mfma_f32_16x16x32_bf16(av, bv, acc[cf], 0, 0, 0);
            }
        }
        __syncthreads();
        cur = nxt;
    }
    // ---- epilogue ----
    // transpose-store acc to t_lds bf16 + score partials
    float p1[4] = {0.f, 0.f, 0.f, 0.f}, p2[4] = {0.f, 0.f, 0.f, 0.f};
    const float* ah = avec + (size_t)h * 2 * F;
    #pragma unroll
    for (int cf = 0; cf < NCF; ++cf) {
        int col = c0 + cf * 16 + krow;
        float aw1 = ah[col], aw2 = ah[F + col];
        #pragma unroll
        for (int r = 0; r < 4; ++r) {
            int row = r0 + kgrp * 4 + r;
            t_lds[col * 40 + row] = f2bf(acc[cf][r]);
            p1[r] += acc[cf][r] * aw1;
            p2[r] += acc[cf][r] * aw2;
        }
    }
    #pragma unroll
    for (int d = 1; d < 16; d <<= 1) {
        #pragma unroll
        for (int r = 0; r < 4; ++r) { p1[r] += __shfl_xor(p1[r], d); p2[r] += __shfl_xor(p2[r], d); }
    }
    if (krow == 0) {
        #pragma unroll
        for (int r = 0; r < 4; ++r) {
            int row = r0 + kgrp * 4 + r;
            atomicAdd(&sred[row][0], p1[r]);
            atomicAdd(&sred[row][1], p2[r]);
        }
    }
    __syncthreads();
    {
        int col = t >> 2, seg = (t & 3) * 8;
        if (col < F) {
            uint4 v = *(const uint4*)&t_lds[col * 40 + seg];
            int jb = i0 >> 7, jl = (i0 & 127) + seg;   // j-tiled store
            *(uint4*)&WhT[(((size_t)h * (NN / 128) + jb) * F + col) * 128 + jl] = v;
        }
    }
    if (t < BM) {
        s1g[(size_t)h * NN + i0 + t] = sred[t][0] * LOG2E;
        s2g[(size_t)h * NN + i0 + t] = sred[t][1] * LOG2E;
    }
    if (w == 0) {
        float v = (t < BM) ? sred[t][1] * LOG2E : -3.4e38f;
        #pragma unroll
        for (int d = 1; d < 64; d <<= 1) v = fmaxf(v, __shfl_xor(v, d));
        if (lane == 0) {
            uint32_t b = __float_as_uint(v);
            uint32_t key = (b & 0x80000000u) ? ~b : (b | 0x80000000u);
            atomicMax(smaxKey + h, key);
        }
    }
}

// ---------------- prep: E1 = 2^(q-S), E2 = 2^(0.2(q-S)) per (h, j) ----------------
// Moves all per-element transcendentals out of the aggregation inner loop:
// p = 2^max(q+c1, 0.2q+c2) == max(E1*K1, E2*K2) with K1=2^min(0,z), K2=2^min(0,-z),
// z = 0.8(s1+S) (verified identical on both lrelu branches); all factors <= 1.
__global__ void k_prepE(const float* __restrict__ s2, const unsigned int* __restrict__ keyp,
                        float* __restrict__ e1, float* __restrict__ e2) {
    int idx = blockIdx.x * 256 + threadIdx.x;
    int h = idx >> 12;                 // NN = 4096
    unsigned int kk = keyp[h];
    float smax = __uint_as_float((kk & 0x80000000u) ? (kk ^ 0x80000000u) : ~kk);
    float d = s2[idx] - smax;          // <= 0
    e1[idx] = exp2_fast(d);
    e2[idx] = exp2_fast(0.2f * d);
}

// ---------------- register-P MFMA masked-softmax aggregation (R3 structure, tiled src) ----
// NW waves; NJH j-slices; rg = w/NJH owns 32 rows, jh = w%NJH owns K=32 of TJ=128.
// WhT is j-tiled: stage reads ONE CONTIGUOUS 32KB block per tile (the R2..R7 scatter
// eliminated). LDS swizzle: source unit pre-swizzled srcu = f*16 + (jg ^ (f&7)) with
// linear glds16 dest; ds_read applies the same XOR -> 2-way conflicts (free).
// Inner loop has ZERO transcendentals: p = mask ? max(e1*K1, e2*K2) : 0.
// Sync: R3's raw-barrier counted-wait loop (computeP(sd[t+1]) waits loads issued after
// stage(t) -> drains stage(t) per-wave; barrier makes it block-wide; stage(t+1) stays
// in flight across the barrier; tri-buffer covers the WAR).
template <int F, int NW, int NJH>
__global__ __launch_bounds__(NW * 64, 4)
void k_agg8(const unsigned short* __restrict__ WhT, const float* __restrict__ s1v,
            const float* __restrict__ E1v, const float* __restrict__ E2v,
            const unsigned int* __restrict__ smaxKey,
            const unsigned char* __restrict__ bmb,
            float* __restrict__ pnum, float* __restrict__ pden, int njt, int nh) {
    constexpr int TI = (NW / NJH) * 32, TJ = NJH * 32;
    constexpr int NB = F / 16;            // B frags per wave
    constexpr int CPR = TJ / 8;           // mask bytes per tile row
    constexpr int TUNITS = F * (TJ / 8);  // 16B units per tile
    constexpr int CH_W = TUNITS / NW;     // units staged per wave
    constexpr int XF = F + 4;             // padded exchange stride (words)
    constexpr int XROWS = TI / 2;
    constexpr size_t ST_BYTES = sizeof(unsigned short) * 3 * F * TJ;
    constexpr size_t XCH_BYTES = sizeof(float) * (size_t)(NJH - 1) * XROWS * XF;
    constexpr size_t SM_BYTES = ST_BYTES > XCH_BYTES ? ST_BYTES : XCH_BYTES;
    __shared__ __align__(16) char smem[SM_BYTES];
    __shared__ float den_sh[NJH][TI];
    auto whT_lds = (unsigned short (*)[F * TJ])smem;
    float* xch = (float*)smem;
    int t = threadIdx.x, l = t & 63, w = t >> 6;
    int h = blockIdx.y, js = blockIdx.z;
    int i0 = blockIdx.x * TI;
    int rg = w / NJH, jh = w % NJH;
    int r0 = rg * 32;
    const unsigned short* WhTt = WhT + (size_t)h * (NN / 128) * (F * 128);
    const float* E1h = E1v + (size_t)h * NN;
    const float* E2h = E2v + (size_t)h * NN;
    unsigned int kk = smaxKey[h];
    float smax = __uint_as_float((kk & 0x80000000u) ? (kk ^ 0x80000000u) : ~kk);
    int lane16 = l & 15, kgrp = l >> 4;
    int rowA = i0 + r0 + lane16;
    int rowB = rowA + 16;
    float s1A = s1v[(size_t)h * NN + rowA];
    float s1B = s1v[(size_t)h * NN + rowB];
    float zA = 0.8f * (s1A + smax), zB = 0.8f * (s1B + smax);
    float K1A = exp2_fast(fminf(zA, 0.f)), K2A = exp2_fast(fminf(-zA, 0.f));
    float K1B = exp2_fast(fminf(zB, 0.f)), K2B = exp2_fast(fminf(-zB, 0.f));
    int joff = jh * 32 + kgrp * 8;
    int jsbase = js * njt;
    const unsigned char* bmbA = bmb + (size_t)rowA * 512;
    const unsigned char* bmbB = bmb + (size_t)rowB * 512;

    f32x4 acc[2][NB];
    #pragma unroll
    for (int m = 0; m < 2; ++m)
        #pragma unroll
        for (int b = 0; b < NB; ++b) acc[m][b] = (f32x4){0.f, 0.f, 0.f, 0.f};
    float denA = 0.f, denB = 0.f;

    struct SD { float4 a0, a1, b0, b1; unsigned int mA, mB; };
    struct PA { short8 a, b; };

    auto loadSD = [&](int jt) {
        SD s;
        int j0 = (jsbase + jt) * TJ;
        s.a0 = *(const float4*)&E1h[j0 + joff];
        s.a1 = *(const float4*)&E1h[j0 + joff + 4];
        s.b0 = *(const float4*)&E2h[j0 + joff];
        s.b1 = *(const float4*)&E2h[j0 + joff + 4];
        int wb = (jsbase + jt) * CPR + jh * 4 + kgrp;
        s.mA = bmbA[wb];
        s.mB = bmbB[wb];
        return s;
    };

    auto computeP = [&](const SD& s) {
        float e1v[8] = {s.a0.x, s.a0.y, s.a0.z, s.a0.w, s.a1.x, s.a1.y, s.a1.z, s.a1.w};
        float e2v[8] = {s.b0.x, s.b0.y, s.b0.z, s.b0.w, s.b1.x, s.b1.y, s.b1.z, s.b1.w};
        float pA[8], pB[8];
        #pragma unroll
        for (int u = 0; u < 8; ++u) {
            float vA = fmaxf(e1v[u] * K1A, e2v[u] * K2A);
            vA = ((s.mA >> u) & 1u) ? vA : 0.f;
            denA += vA; pA[u] = vA;
            float vB = fmaxf(e1v[u] * K1B, e2v[u] * K2B);
            vB = ((s.mB >> u) & 1u) ? vB : 0.f;
            denB += vB; pB[u] = vB;
        }
        union { uint32_t d[4]; short8 v; } ua, ub;
        #pragma unroll
        for (int j = 0; j < 4; ++j) {
            ua.d[j] = cvt_pk_bf16(pA[2 * j], pA[2 * j + 1]);
            ub.d[j] = cvt_pk_bf16(pB[2 * j], pB[2 * j + 1]);
        }
        PA p; p.a = ua.v; p.b = ub.v;
        return p;
    };

    // contiguous tiled staging with source-side swizzle: LDS unit c holds global
    // unit f*16 + (jg ^ (f&7)), f = c>>4, jg = c&15. Wave reads permuted-contiguous
    // 1KB per glds16 (all 64B sectors covered -> fully coalesced).
    auto stage = [&](int buf, int jt) {
        const unsigned short* base = WhTt + (size_t)(jsbase + jt) * (F * 128);
        #pragma unroll
        for (int s = 0; s < CH_W / 64; ++s) {
            int c = w * CH_W + s * 64 + l;
            int f = c >> 4, jg = c & 15;
            int srcu = f * 16 + (jg ^ (f & 7));
            glds16(base + (size_t)srcu * 8, &whT_lds[buf][(w * CH_W + s * 64) * 8]);
        }
    };

    // bv = feature row f = b*16+lane16, 8 j at (jh*4+kgrp)*8; 2-way bank alias (free)
    auto domfma = [&](int buf, const PA& pa) {
        int joff2 = jh * 4 + kgrp;
        #pragma unroll
        for (int b = 0; b < NB; ++b) {
            int f = b * 16 + lane16;
            int unit = f * 16 + (joff2 ^ (f & 7));
            short8 bv = *(const short8*)&whT_lds[buf][unit * 8];
            acc[0][b] = __builtin_amdgcn_mfma_f32_16x16x32_bf16(pa.a, bv, acc[0][b], 0, 0, 0);
            acc[1][b] = __builtin_amdgcn_mfma_f32_16x16x32_bf16(pa.b, bv, acc[1][b], 0, 0, 0);
        }
    };

    // prologue (iter-0's pre-barrier wait covers stage(0))
    SD sd_cur = loadSD(0);
    __builtin_amdgcn_sched_barrier(0);
    stage(0, 0);
    __builtin_amdgcn_sched_barrier(0);
    SD sd_nxt;
    if (njt > 1) sd_nxt = loadSD(1);
    PA pa_cur = computeP(sd_cur);
    int cur = 0, nx1 = 1;
    for (int jt = 0; jt < njt; ++jt) {
        bool more = jt + 1 < njt;
        if (more) stage(nx1, jt + 1);
        __builtin_amdgcn_sched_barrier(0);   // pin: stage glds16 precede newer loads
        SD sd2;
        if (jt + 2 < njt) sd2 = loadSD(jt + 2);
        PA pa_n;
        if (more) pa_n = computeP(sd_nxt);   // waits loadSD(jt+1) -> drains stage(jt)
        __builtin_amdgcn_sched_barrier(0);
        if (!more) asm volatile("s_waitcnt vmcnt(0)" ::: "memory");
        __builtin_amdgcn_s_barrier();        // raw: stage(jt+1) stays in flight
        __builtin_amdgcn_sched_barrier(0);
        domfma(cur, pa_cur);
        pa_cur = pa_n;
        sd_nxt = sd2;
        cur = nx1;
        nx1 = nx1 + 1 == 3 ? 0 : nx1 + 1;
    }

    // den: sum k-groups (lanes sharing l&15)
    denA += __shfl_xor(denA, 16); denA += __shfl_xor(denA, 32);
    denB += __shfl_xor(denB, 16); denB += __shfl_xor(denB, 32);
    if (l < 16) {
        den_sh[jh][r0 + l] = denA;
        den_sh[jh][r0 + 16 + l] = denB;
    }
    __syncthreads();

    // merge jh slices of acc via LDS (two row-passes), write pnum
    float* pnumS = pnum + ((size_t)(js * nh + h) * NN + i0) * F;
    #pragma unroll
    for (int m = 0; m < 2; ++m) {
        if (jh > 0) {
            float* sl = xch + (size_t)(jh - 1) * XROWS * XF;
            #pragma unroll
            for (int b = 0; b < NB; ++b) {
                int col = b * 16 + lane16;
                #pragma unroll
                for (int r = 0; r < 4; ++r)
                    sl[(rg * 16 + kgrp * 4 + r) * XF + col] = acc[m][b][r];
            }
        }
        __syncthreads();
        if (jh == 0) {
            #pragma unroll
            for (int b = 0; b < NB; ++b) {
                int col = b * 16 + lane16;
                #pragma unroll
                for (int r = 0; r < 4; ++r) {
                    int lrow = rg * 16 + kgrp * 4 + r;
                    int row = r0 + m * 16 + kgrp * 4 + r;
                    float v = acc[m][b][r];
                    #pragma unroll
                    for (int sX = 1; sX < NJH; ++sX)
                        v += xch[((size_t)(sX - 1) * XROWS + lrow) * XF + col];
                    pnumS[(size_t)row * F + col] = v;
                }
            }
        }
        __syncthreads();
    }
    if (t < TI) {
        float d = den_sh[0][t];
        #pragma unroll
        for (int sX = 1; sX < NJH; ++sX) d += den_sh[sX][t];
        pden[(size_t)(js * nh + h) * NN + i0 + t] = d;
    }
}

// ---------------- reduce layer-1 partials -> hbuf bf16 (with ELU) ----------------
__global__ void k_reduce1(const float* __restrict__ pnum, const float* __restrict__ pden,
                          unsigned short* __restrict__ hbuf) {
    int idx = blockIdx.x * 256 + threadIdx.x;   // NN*128 float4s
    int i = idx >> 7;
    int c4 = idx & 127;
    int hh = c4 >> 5, f4 = c4 & 31;
    float4 a = *(const float4*)&pnum[((size_t)hh * NN + i) * 128 + f4 * 4];
    float4 b = *(const float4*)&pnum[((size_t)(4 + hh) * NN + i) * 128 + f4 * 4];
    float den = pden[(size_t)hh * NN + i] + pden[(size_t)(4 + hh) * NN + i];
    float inv = 1.f / den;
    float v[4] = {(a.x + b.x) * inv, (a.y + b.y) * inv, (a.z + b.z) * inv, (a.w + b.w) * inv};
    uint2 o;
    unsigned short e[4];
    #pragma unroll
    for (int u = 0; u < 4; ++u) {
        float x = v[u];
        x = x > 0.f ? x : expm1f(x);
        e[u] = f2bf(x);
    }
    o.x = (uint32_t)e[0] | ((uint32_t)e[1] << 16);
    o.y = (uint32_t)e[2] | ((uint32_t)e[3] << 16);
    *(uint2*)&hbuf[(size_t)i * 512 + c4 * 4] = o;
}

// ---------------- reduce layer-2 partials -> out f32 ----------------
__global__ void k_reduce2(const float* __restrict__ pnum, const float* __restrict__ pden,
                          float* __restrict__ out) {
    int idx = blockIdx.x * 256 + threadIdx.x;   // NN*16 float4s
    int i = idx >> 4;
    int f4 = (idx & 15) * 4;
    float4 s = {0.f, 0.f, 0.f, 0.f};
    float den = 0.f;
    #pragma unroll
    for (int js = 0; js < 8; ++js) {
        float4 v = *(const float4*)&pnum[((size_t)js * NN + i) * 64 + f4];
        s.x += v.x; s.y += v.y; s.z += v.z; s.w += v.w;
        den += pden[(size_t)js * NN + i];
    }
    float inv = 1.f / den;
    s.x *= inv; s.y *= inv; s.z *= inv; s.w *= inv;
    *(float4*)&out[(size_t)i * 64 + f4] = s;
}

extern "C" void kernel_launch(void* const* d_in, const int* in_sizes, int n_in,
                              void* d_out, int out_size, void* d_ws, size_t ws_size,
                              hipStream_t stream) {
    const int*   g      = (const int*)d_in[0];
    const float* inputs = (const float*)d_in[1];
    const float* W1     = (const float*)d_in[2];
    const float* a1     = (const float*)d_in[3];
    const float* W2     = (const float*)d_in[4];
    const float* a2     = (const float*)d_in[5];
    float* out = (float*)d_out;
    char* ws = (char*)d_ws;

    size_t off = 0;
    uint64_t* bm   = (uint64_t*)(ws + off); off += (size_t)NN * 64 * 8;              // 2 MB
    unsigned short* Xbf  = (unsigned short*)(ws + off); off += (size_t)NN * KD * 2;  // 4 MB
    unsigned short* W1T  = (unsigned short*)(ws + off); off += (size_t)4 * 128 * KD * 2;
    unsigned short* W2T  = (unsigned short*)(ws + off); off += (size_t)64 * KD * 2;
    unsigned short* WhT1 = (unsigned short*)(ws + off); off += (size_t)4 * 128 * NN * 2; // 4 MB (tiled)
    unsigned short* WhT2 = (unsigned short*)(ws + off); off += (size_t)64 * NN * 2;      // 0.5 MB (tiled)
    unsigned short* hbuf = (unsigned short*)(ws + off); off += (size_t)NN * KD * 2;      // 4 MB
    float* s1_1    = (float*)(ws + off);    off += (size_t)4 * NN * 4;
    float* s2_1    = (float*)(ws + off);    off += (size_t)4 * NN * 4;
    float* s1_2    = (float*)(ws + off);    off += (size_t)NN * 4;
    float* s2_2    = (float*)(ws + off);    off += (size_t)NN * 4;
    float* e1_1    = (float*)(ws + off);    off += (size_t)4 * NN * 4;
    float* e2_1    = (float*)(ws + off);    off += (size_t)4 * NN * 4;
    float* e1_2    = (float*)(ws + off);    off += (size_t)NN * 4;
    float* e2_2    = (float*)(ws + off);    off += (size_t)NN * 4;
    unsigned int* keys = (unsigned int*)(ws + off); off += 256;   // [0..3] l1, [4] l2
    float* pnum    = (float*)(ws + off);    off += (size_t)8 * NN * 128 * 4;         // 16 MB
    float* pden    = (float*)(ws + off);    off += (size_t)8 * NN * 4;               // 128 KB
    // layer-2 partials alias layer-1's (serial stream, disjoint lifetime)
    float* pnum2 = pnum;
    float* pden2 = pden;

    hipMemsetAsync(keys, 0, 32, stream);
    k_bitmask<<<NN / 4, 256, 0, stream>>>(g, bm);
    k_cast<<<(NN * KD / 4 + 255) / 256, 256, 0, stream>>>(inputs, Xbf, NN * KD / 4);
    k_tc<<<dim3(KD / 64, 2, 4), 256, 0, stream>>>(W1, W1T, KD, 128);
    k_tc<<<dim3(KD / 64, 1, 1), 256, 0, stream>>>(W2, W2T, KD, 64);
    // layer 1
    k_gemm_fused<128><<<dim3(NN / 32, 4), 512, 0, stream>>>(Xbf, W1T, a1, WhT1, s1_1, s2_1, keys);
    k_prepE<<<4 * NN / 256, 256, 0, stream>>>(s2_1, keys, e1_1, e2_1);
    k_agg8<128, 16, 4><<<dim3(NN / 128, 4, 2), 1024, 0, stream>>>(
        WhT1, s1_1, e1_1, e2_1, keys, (const unsigned char*)bm, pnum, pden, NN / 128 / 2, 4);
    k_reduce1<<<NN * 128 / 256, 256, 0, stream>>>(pnum, pden, hbuf);
    // layer 2
    k_gemm_fused<64><<<dim3(NN / 32, 1), 512, 0, stream>>>(hbuf, W2T, a2, WhT2, s1_2, s2_2, keys + 4);
    k_prepE<<<NN / 256, 256, 0, stream>>>(s2_2, keys + 4, e1_2, e2_2);
    k_agg8<64, 8, 4><<<dim3(NN / 64, 1, 8), 512, 0, stream>>>(
        WhT2, s1_2, e1_2, e2_2, keys + 4, (const unsigned char*)bm, pnum2, pden2, NN / 128 / 8, 1);
    k_reduce2<<<NN * 16 / 256, 256, 0, stream>>>(pnum2, pden2, out);
}

// Round 9
// 198.079 us; speedup vs baseline: 1.0745x; 1.0745x over previous
//
#include <hip/hip_runtime.h>
#include <hip/hip_bf16.h>
#include <stdint.h>

#define NN 4096      // nodes
#define KD 512       // input dim of both GEMMs (512 = IN_DIM = HID*HEADS)
#define LOG2E 1.4426950408889634f

typedef __attribute__((ext_vector_type(8))) short short8;
typedef __attribute__((ext_vector_type(4))) float f32x4;

__device__ __forceinline__ float lrelu(float x) { return fmaxf(x, 0.2f * x); }

__device__ __forceinline__ unsigned short f2bf(float f) {
    uint32_t u = __float_as_uint(f);
    u += 0x7fff + ((u >> 16) & 1);           // RNE
    return (unsigned short)(u >> 16);
}

// 2^x via hardware transcendental (scores are pre-scaled by log2e)
__device__ __forceinline__ float exp2_fast(float x) {
    float r; asm("v_exp_f32 %0, %1" : "=v"(r) : "v"(x)); return r;
}

// pack 2 f32 -> 2 bf16 (RNE), lo -> [15:0], hi -> [31:16]
__device__ __forceinline__ uint32_t cvt_pk_bf16(float lo, float hi) {
    uint32_t r; asm("v_cvt_pk_bf16_f32 %0, %1, %2" : "=v"(r) : "v"(lo), "v"(hi)); return r;
}

// async global->LDS, 16B per lane; lds ptr must be wave-uniform base
__device__ __forceinline__ void glds16(const void* g, void* l) {
    __builtin_amdgcn_global_load_lds(
        (const __attribute__((address_space(1))) uint32_t*)g,
        (__attribute__((address_space(3))) uint32_t*)l, 16, 0, 0);
}

// ---------------- bitmask: g[N][N] int32 -> bm[N][64] uint64 ----------------
__global__ void k_bitmask(const int* __restrict__ g, uint64_t* __restrict__ bm) {
    int wave = threadIdx.x >> 6;
    int lane = threadIdx.x & 63;
    int row = blockIdx.x * 4 + wave;
    const int* grow = g + (size_t)row * NN;
    #pragma unroll 4
    for (int w = 0; w < 64; ++w) {
        int v = grow[w * 64 + lane];
        unsigned long long m = __ballot(v > 0);
        if (lane == 0) bm[(size_t)row * 64 + w] = m;
    }
}

// ---------------- cast f32 -> bf16 (vectorized) ----------------
__global__ void k_cast(const float* __restrict__ x, unsigned short* __restrict__ y, int n4) {
    int i = blockIdx.x * 256 + threadIdx.x;
    if (i < n4) {
        float4 v = ((const float4*)x)[i];
        uint2 o;
        o.x = (uint32_t)f2bf(v.x) | ((uint32_t)f2bf(v.y) << 16);
        o.y = (uint32_t)f2bf(v.z) | ((uint32_t)f2bf(v.w) << 16);
        ((uint2*)y)[i] = o;
    }
}

// ---------------- generic transpose+cast: src f32 [b][R][C] -> dst bf16 [b][C][R] ----------------
__global__ __launch_bounds__(256)
void k_tc(const float* __restrict__ src, unsigned short* __restrict__ dst, int R, int C) {
    __shared__ float tile[64][65];
    int b = blockIdx.z;
    int r0 = blockIdx.x * 64, c0 = blockIdx.y * 64;
    src += (size_t)b * R * C;
    dst += (size_t)b * C * R;
    int t = threadIdx.x;
    #pragma unroll
    for (int s = 0; s < 16; ++s) {
        int idx = t + s * 256;
        int r = idx >> 6, c = idx & 63;
        tile[r][c] = src[(size_t)(r0 + r) * C + c0 + c];
    }
    __syncthreads();
    #pragma unroll
    for (int s = 0; s < 16; ++s) {
        int idx = t + s * 256;
        int r = idx >> 6, c = idx & 63;
        dst[(size_t)(c0 + r) * R + r0 + c] = f2bf(tile[c][r]);
    }
}

// ---------------- fused MFMA GEMM: Wh = A @ W, epilogue writes FRAGMENT-ORDER tiled WhT ----
// A bf16 [NN][512], WT bf16 [nh][F][512]. BM=32, BK=64, 8 waves (2row x 4col).
// WhT layout: [h][j/128][unit][8] where 16B unit = (fb*256 + jsl*16 + r):
//   feature row = fb*16 + r, j = jtile*128 + jsl*8 .. +8.
// This is EXACTLY the LDS image the aggregation kernel consumes, so its glds16 staging
// source is linear lane-monotonic contiguous 1KB (fully coalesced -- R8's swizzled
// source broke glds coalescing, 4x FETCH) and its ds_read is R3's frag-order pattern
// (measured 0 conflicts). s1/s2/smax are written PRE-SCALED by log2(e).
template <int F>
__global__ __launch_bounds__(512)
void k_gemm_fused(const unsigned short* __restrict__ Abf, const unsigned short* __restrict__ WT,
                  const float* __restrict__ avec,
                  unsigned short* __restrict__ WhT, float* __restrict__ s1g,
                  float* __restrict__ s2g, unsigned int* __restrict__ smaxKey) {
    constexpr int BM = 32, BK = 64;
    constexpr int NCF = F / 64;
    __shared__ unsigned short a_lds[2][BM * BK];
    __shared__ unsigned short b_lds[2][F * BK];
    __shared__ unsigned short t_lds[F * 40];
    __shared__ float sred[BM][2];
    int t = threadIdx.x, lane = t & 63, w = t >> 6;
    int h = blockIdx.y;
    int i0 = blockIdx.x * BM;
    const unsigned short* WTh = WT + (size_t)h * F * KD;
    int r0 = (w >> 2) * 16, c0 = (w & 3) * (F / 4);
    int krow = lane & 15, kgrp = lane >> 4;
    if (t < BM) { sred[t][0] = 0.f; sred[t][1] = 0.f; }
    f32x4 acc[NCF];
    #pragma unroll
    for (int cf = 0; cf < NCF; ++cf) acc[cf] = (f32x4){0.f, 0.f, 0.f, 0.f};

    auto stage = [&](int buf, int kt) {
        int k0 = kt * BK;
        if (w < 4) {            // A tile: 256 chunks
            int c = w * 64 + lane;
            int row = c >> 3, slot = c & 7;
            glds16(Abf + (size_t)(i0 + row) * KD + k0 + ((slot ^ (row & 7)) * 8),
                   &a_lds[buf][(w * 64) * 8]);
        }
        #pragma unroll
        for (int s = 0; s < F / 64; ++s) {   // B tile: 8F chunks
            int c = w * F + s * 64 + lane;
            int row = c >> 3, slot = c & 7;
            glds16(WTh + (size_t)row * KD + k0 + ((slot ^ (row & 7)) * 8),
                   &b_lds[buf][(w * F + s * 64) * 8]);
        }
    };

    stage(0, 0);
    __syncthreads();
    int cur = 0;
    for (int kt = 0; kt < KD / BK; ++kt) {
        int nxt = cur ^ 1;
        if (kt + 1 < KD / BK) stage(nxt, kt + 1);
        #pragma unroll
        for (int ks = 0; ks < 2; ++ks) {
            int koff = ks * 32 + kgrp * 8;
            int arow = r0 + krow;
            short8 av = *(const short8*)((const char*)&a_lds[cur][arow * BK] +
                                         ((koff * 2) ^ ((arow & 7) << 4)));
            #pragma unroll
            for (int cf = 0; cf < NCF; ++cf) {
                int brow = c0 + cf * 16 + krow;
                short8 bv = *(const short8*)((const char*)&b_lds[cur][brow * BK] +
                                             ((koff * 2) ^ ((brow & 7) << 4)));
                acc[cf] = __builtin_amdgcn_mfma_f32_16x16x32_bf16(av, bv, acc[cf], 0, 0, 0);
            }
        }
        __syncthreads();
        cur = nxt;
    }
    // ---- epilogue ----
    // transpose-store acc to t_lds bf16 + score partials
    float p1[4] = {0.f, 0.f, 0.f, 0.f}, p2[4] = {0.f, 0.f, 0.f, 0.f};
    const float* ah = avec + (size_t)h * 2 * F;
    #pragma unroll
    for (int cf = 0; cf < NCF; ++cf) {
        int col = c0 + cf * 16 + krow;
        float aw1 = ah[col], aw2 = ah[F + col];
        #pragma unroll
        for (int r = 0; r < 4; ++r) {
            int row = r0 + kgrp * 4 + r;
            t_lds[col * 40 + row] = f2bf(acc[cf][r]);
            p1[r] += acc[cf][r] * aw1;
            p2[r] += acc[cf][r] * aw2;
        }
    }
    #pragma unroll
    for (int d = 1; d < 16; d <<= 1) {
        #pragma unroll
        for (int r = 0; r < 4; ++r) { p1[r] += __shfl_xor(p1[r], d); p2[r] += __shfl_xor(p2[r], d); }
    }
    if (krow == 0) {
        #pragma unroll
        for (int r = 0; r < 4; ++r) {
            int row = r0 + kgrp * 4 + r;
            atomicAdd(&sred[row][0], p1[r]);
            atomicAdd(&sred[row][1], p2[r]);
        }
    }
    __syncthreads();
    {
        int col = t >> 2, seg = (t & 3) * 8;
        if (col < F) {
            uint4 v = *(const uint4*)&t_lds[col * 40 + seg];
            int jb = i0 >> 7, jl = (i0 & 127) + seg;   // fragment-order tiled store
            int unit = (col >> 4) * 256 + (jl >> 3) * 16 + (col & 15);
            *(uint4*)&WhT[((size_t)h * (NN / 128) + jb) * ((size_t)F * 128) + (size_t)unit * 8] = v;
        }
    }
    if (t < BM) {
        s1g[(size_t)h * NN + i0 + t] = sred[t][0] * LOG2E;
        s2g[(size_t)h * NN + i0 + t] = sred[t][1] * LOG2E;
    }
    if (w == 0) {
        float v = (t < BM) ? sred[t][1] * LOG2E : -3.4e38f;
        #pragma unroll
        for (int d = 1; d < 64; d <<= 1) v = fmaxf(v, __shfl_xor(v, d));
        if (lane == 0) {
            uint32_t b = __float_as_uint(v);
            uint32_t key = (b & 0x80000000u) ? ~b : (b | 0x80000000u);
            atomicMax(smaxKey + h, key);
        }
    }
}

// ---------------- prep: E1 = 2^(q-S), E2 = 2^(0.2(q-S)) per (h, j) ----------------
// p = 2^max(q+c1, 0.2q+c2) == max(E1*K1, E2*K2) with K1=2^min(0,z), K2=2^min(0,-z),
// z = 0.8(s1+S) (identical on both lrelu branches); all factors <= 1.
__global__ void k_prepE(const float* __restrict__ s2, const unsigned int* __restrict__ keyp,
                        float* __restrict__ e1, float* __restrict__ e2) {
    int idx = blockIdx.x * 256 + threadIdx.x;
    int h = idx >> 12;                 // NN = 4096
    unsigned int kk = keyp[h];
    float smax = __uint_as_float((kk & 0x80000000u) ? (kk ^ 0x80000000u) : ~kk);
    float d = s2[idx] - smax;          // <= 0
    e1[idx] = exp2_fast(d);
    e2[idx] = exp2_fast(0.2f * d);
}

// ---------------- register-P MFMA masked-softmax aggregation (R3 structure, frag-tiled src) ----
// NW waves; NJH j-slices; rg = w/NJH owns 32 rows, jh = w%NJH owns K=32 of TJ=128.
// WhT tiles are stored in FRAGMENT ORDER: glds16 source is linear lane-monotonic
// (contiguous 1KB per instr -> fully coalesced), LDS unit index == global unit index,
// ds_read is R3's frag-order pattern (0 conflicts measured). No swizzle anywhere.
// Inner loop has ZERO transcendentals (prepE factorization).
// Sync: R3's raw-barrier counted-wait loop; tri-buffer covers the WAR.
template <int F, int NW, int NJH>
__global__ __launch_bounds__(NW * 64, 4)
void k_agg9(const unsigned short* __restrict__ WhT, const float* __restrict__ s1v,
            const float* __restrict__ E1v, const float* __restrict__ E2v,
            const unsigned int* __restrict__ smaxKey,
            const unsigned char* __restrict__ bmb,
            float* __restrict__ pnum, float* __restrict__ pden, int njt, int nh) {
    constexpr int TI = (NW / NJH) * 32, TJ = NJH * 32;
    constexpr int NB = F / 16;            // B frags per wave
    constexpr int CPR = TJ / 8;           // mask bytes per tile row
    constexpr int TUNITS = F * (TJ / 8);  // 16B units per tile
    constexpr int CH_W = TUNITS / NW;     // units staged per wave
    constexpr int XF = F + 4;             // padded exchange stride (words)
    constexpr int XROWS = TI / 2;
    constexpr size_t ST_BYTES = sizeof(unsigned short) * 3 * F * TJ;
    constexpr size_t XCH_BYTES = sizeof(float) * (size_t)(NJH - 1) * XROWS * XF;
    constexpr size_t SM_BYTES = ST_BYTES > XCH_BYTES ? ST_BYTES : XCH_BYTES;
    __shared__ __align__(16) char smem[SM_BYTES];
    __shared__ float den_sh[NJH][TI];
    auto whT_lds = (unsigned short (*)[F * TJ])smem;
    float* xch = (float*)smem;
    int t = threadIdx.x, l = t & 63, w = t >> 6;
    int h = blockIdx.y, js = blockIdx.z;
    int i0 = blockIdx.x * TI;
    int rg = w / NJH, jh = w % NJH;
    int r0 = rg * 32;
    const unsigned short* WhTt = WhT + (size_t)h * (NN / 128) * ((size_t)F * 128);
    const float* E1h = E1v + (size_t)h * NN;
    const float* E2h = E2v + (size_t)h * NN;
    unsigned int kk = smaxKey[h];
    float smax = __uint_as_float((kk & 0x80000000u) ? (kk ^ 0x80000000u) : ~kk);
    int lane16 = l & 15, kgrp = l >> 4;
    int rowA = i0 + r0 + lane16;
    int rowB = rowA + 16;
    float s1A = s1v[(size_t)h * NN + rowA];
    float s1B = s1v[(size_t)h * NN + rowB];
    float zA = 0.8f * (s1A + smax), zB = 0.8f * (s1B + smax);
    float K1A = exp2_fast(fminf(zA, 0.f)), K2A = exp2_fast(fminf(-zA, 0.f));
    float K1B = exp2_fast(fminf(zB, 0.f)), K2B = exp2_fast(fminf(-zB, 0.f));
    int joff = jh * 32 + kgrp * 8;
    int jsbase = js * njt;
    const unsigned char* bmbA = bmb + (size_t)rowA * 512;
    const unsigned char* bmbB = bmb + (size_t)rowB * 512;

    f32x4 acc[2][NB];
    #pragma unroll
    for (int m = 0; m < 2; ++m)
        #pragma unroll
        for (int b = 0; b < NB; ++b) acc[m][b] = (f32x4){0.f, 0.f, 0.f, 0.f};
    float denA = 0.f, denB = 0.f;

    struct SD { float4 a0, a1, b0, b1; unsigned int mA, mB; };
    struct PA { short8 a, b; };

    auto loadSD = [&](int jt) {
        SD s;
        int j0 = (jsbase + jt) * TJ;
        s.a0 = *(const float4*)&E1h[j0 + joff];
        s.a1 = *(const float4*)&E1h[j0 + joff + 4];
        s.b0 = *(const float4*)&E2h[j0 + joff];
        s.b1 = *(const float4*)&E2h[j0 + joff + 4];
        int wb = (jsbase + jt) * CPR + jh * 4 + kgrp;
        s.mA = bmbA[wb];
        s.mB = bmbB[wb];
        return s;
    };

    auto computeP = [&](const SD& s) {
        float e1v[8] = {s.a0.x, s.a0.y, s.a0.z, s.a0.w, s.a1.x, s.a1.y, s.a1.z, s.a1.w};
        float e2v[8] = {s.b0.x, s.b0.y, s.b0.z, s.b0.w, s.b1.x, s.b1.y, s.b1.z, s.b1.w};
        float pA[8], pB[8];
        #pragma unroll
        for (int u = 0; u < 8; ++u) {
            float vA = fmaxf(e1v[u] * K1A, e2v[u] * K2A);
            vA = ((s.mA >> u) & 1u) ? vA : 0.f;
            denA += vA; pA[u] = vA;
            float vB = fmaxf(e1v[u] * K1B, e2v[u] * K2B);
            vB = ((s.mB >> u) & 1u) ? vB : 0.f;
            denB += vB; pB[u] = vB;
        }
        union { uint32_t d[4]; short8 v; } ua, ub;
        #pragma unroll
        for (int j = 0; j < 4; ++j) {
            ua.d[j] = cvt_pk_bf16(pA[2 * j], pA[2 * j + 1]);
            ub.d[j] = cvt_pk_bf16(pB[2 * j], pB[2 * j + 1]);
        }
        PA p; p.a = ua.v; p.b = ub.v;
        return p;
    };

    // LINEAR staging: lane l of chunk (w,s) loads global unit c = w*CH_W+s*64+l into
    // LDS unit c. Per instruction: contiguous, lane-monotonic 1KB -> fully coalesced.
    auto stage = [&](int buf, int jt) {
        const unsigned short* base = WhTt + (size_t)(jsbase + jt) * ((size_t)F * 128);
        #pragma unroll
        for (int s = 0; s < CH_W / 64; ++s) {
            int c0u = w * CH_W + s * 64;
            glds16(base + (size_t)(c0u + l) * 8, &whT_lds[buf][c0u * 8]);
        }
    };

    // frag-order read (R3, 0 conflicts): unit = (b*16 + jsl)*16 + r,
    // jsl = jh*4+kgrp, r = lane16 -> 16 lanes read contiguous 256B.
    auto domfma = [&](int buf, const PA& pa) {
        #pragma unroll
        for (int b = 0; b < NB; ++b) {
            int unit = (b * 16 + jh * 4 + kgrp) * 16 + lane16;
            short8 bv = *(const short8*)&whT_lds[buf][unit * 8];
            acc[0][b] = __builtin_amdgcn_mfma_f32_16x16x32_bf16(pa.a, bv, acc[0][b], 0, 0, 0);
            acc[1][b] = __builtin_amdgcn_mfma_f32_16x16x32_bf16(pa.b, bv, acc[1][b], 0, 0, 0);
        }
    };

    // prologue (iter-0's pre-barrier wait covers stage(0))
    SD sd_cur = loadSD(0);
    __builtin_amdgcn_sched_barrier(0);
    stage(0, 0);
    __builtin_amdgcn_sched_barrier(0);
    SD sd_nxt;
    if (njt > 1) sd_nxt = loadSD(1);
    PA pa_cur = computeP(sd_cur);
    int cur = 0, nx1 = 1;
    for (int jt = 0; jt < njt; ++jt) {
        bool more = jt + 1 < njt;
        if (more) stage(nx1, jt + 1);
        __builtin_amdgcn_sched_barrier(0);   // pin: stage glds16 precede newer loads
        SD sd2;
        if (jt + 2 < njt) sd2 = loadSD(jt + 2);
        PA pa_n;
        if (more) pa_n = computeP(sd_nxt);   // waits loadSD(jt+1) -> drains stage(jt)
        __builtin_amdgcn_sched_barrier(0);
        if (!more) asm volatile("s_waitcnt vmcnt(0)" ::: "memory");
        __builtin_amdgcn_s_barrier();        // raw: stage(jt+1) stays in flight
        __builtin_amdgcn_sched_barrier(0);
        domfma(cur, pa_cur);
        pa_cur = pa_n;
        sd_nxt = sd2;
        cur = nx1;
        nx1 = nx1 + 1 == 3 ? 0 : nx1 + 1;
    }

    // den: sum k-groups (lanes sharing l&15)
    denA += __shfl_xor(denA, 16); denA += __shfl_xor(denA, 32);
    denB += __shfl_xor(denB, 16); denB += __shfl_xor(denB, 32);
    if (l < 16) {
        den_sh[jh][r0 + l] = denA;
        den_sh[jh][r0 + 16 + l] = denB;
    }
    __syncthreads();

    // merge jh slices of acc via LDS (two row-passes), write pnum
    float* pnumS = pnum + ((size_t)(js * nh + h) * NN + i0) * F;
    #pragma unroll
    for (int m = 0; m < 2; ++m) {
        if (jh > 0) {
            float* sl = xch + (size_t)(jh - 1) * XROWS * XF;
            #pragma unroll
            for (int b = 0; b < NB; ++b) {
                int col = b * 16 + lane16;
                #pragma unroll
                for (int r = 0; r < 4; ++r)
                    sl[(rg * 16 + kgrp * 4 + r) * XF + col] = acc[m][b][r];
            }
        }
        __syncthreads();
        if (jh == 0) {
            #pragma unroll
            for (int b = 0; b < NB; ++b) {
                int col = b * 16 + lane16;
                #pragma unroll
                for (int r = 0; r < 4; ++r) {
                    int lrow = rg * 16 + kgrp * 4 + r;
                    int row = r0 + m * 16 + kgrp * 4 + r;
                    float v = acc[m][b][r];
                    #pragma unroll
                    for (int sX = 1; sX < NJH; ++sX)
                        v += xch[((size_t)(sX - 1) * XROWS + lrow) * XF + col];
                    pnumS[(size_t)row * F + col] = v;
                }
            }
        }
        __syncthreads();
    }
    if (t < TI) {
        float d = den_sh[0][t];
        #pragma unroll
        for (int sX = 1; sX < NJH; ++sX) d += den_sh[sX][t];
        pden[(size_t)(js * nh + h) * NN + i0 + t] = d;
    }
}

// ---------------- reduce layer-1 partials -> hbuf bf16 (with ELU) ----------------
__global__ void k_reduce1(const float* __restrict__ pnum, const float* __restrict__ pden,
                          unsigned short* __restrict__ hbuf) {
    int idx = blockIdx.x * 256 + threadIdx.x;   // NN*128 float4s
    int i = idx >> 7;
    int c4 = idx & 127;
    int hh = c4 >> 5, f4 = c4 & 31;
    float4 a = *(const float4*)&pnum[((size_t)hh * NN + i) * 128 + f4 * 4];
    float4 b = *(const float4*)&pnum[((size_t)(4 + hh) * NN + i) * 128 + f4 * 4];
    float den = pden[(size_t)hh * NN + i] + pden[(size_t)(4 + hh) * NN + i];
    float inv = 1.f / den;
    float v[4] = {(a.x + b.x) * inv, (a.y + b.y) * inv, (a.z + b.z) * inv, (a.w + b.w) * inv};
    uint2 o;
    unsigned short e[4];
    #pragma unroll
    for (int u = 0; u < 4; ++u) {
        float x = v[u];
        x = x > 0.f ? x : expm1f(x);
        e[u] = f2bf(x);
    }
    o.x = (uint32_t)e[0] | ((uint32_t)e[1] << 16);
    o.y = (uint32_t)e[2] | ((uint32_t)e[3] << 16);
    *(uint2*)&hbuf[(size_t)i * 512 + c4 * 4] = o;
}

// ---------------- reduce layer-2 partials -> out f32 ----------------
__global__ void k_reduce2(const float* __restrict__ pnum, const float* __restrict__ pden,
                          float* __restrict__ out) {
    int idx = blockIdx.x * 256 + threadIdx.x;   // NN*16 float4s
    int i = idx >> 4;
    int f4 = (idx & 15) * 4;
    float4 s = {0.f, 0.f, 0.f, 0.f};
    float den = 0.f;
    #pragma unroll
    for (int js = 0; js < 8; ++js) {
        float4 v = *(const float4*)&pnum[((size_t)js * NN + i) * 64 + f4];
        s.x += v.x; s.y += v.y; s.z += v.z; s.w += v.w;
        den += pden[(size_t)js * NN + i];
    }
    float inv = 1.f / den;
    s.x *= inv; s.y *= inv; s.z *= inv; s.w *= inv;
    *(float4*)&out[(size_t)i * 64 + f4] = s;
}

extern "C" void kernel_launch(void* const* d_in, const int* in_sizes, int n_in,
                              void* d_out, int out_size, void* d_ws, size_t ws_size,
                              hipStream_t stream) {
    const int*   g      = (const int*)d_in[0];
    const float* inputs = (const float*)d_in[1];
    const float* W1     = (const float*)d_in[2];
    const float* a1     = (const float*)d_in[3];
    const float* W2     = (const float*)d_in[4];
    const float* a2     = (const float*)d_in[5];
    float* out = (float*)d_out;
    char* ws = (char*)d_ws;

    size_t off = 0;
    uint64_t* bm   = (uint64_t*)(ws + off); off += (size_t)NN * 64 * 8;              // 2 MB
    unsigned short* Xbf  = (unsigned short*)(ws + off); off += (size_t)NN * KD * 2;  // 4 MB
    unsigned short* W1T  = (unsigned short*)(ws + off); off += (size_t)4 * 128 * KD * 2;
    unsigned short* W2T  = (unsigned short*)(ws + off); off += (size_t)64 * KD * 2;
    unsigned short* WhT1 = (unsigned short*)(ws + off); off += (size_t)4 * 128 * NN * 2; // 4 MB (tiled)
    unsigned short* WhT2 = (unsigned short*)(ws + off); off += (size_t)64 * NN * 2;      // 0.5 MB (tiled)
    unsigned short* hbuf = (unsigned short*)(ws + off); off += (size_t)NN * KD * 2;      // 4 MB
    float* s1_1    = (float*)(ws + off);    off += (size_t)4 * NN * 4;
    float* s2_1    = (float*)(ws + off);    off += (size_t)4 * NN * 4;
    float* s1_2    = (float*)(ws + off);    off += (size_t)NN * 4;
    float* s2_2    = (float*)(ws + off);    off += (size_t)NN * 4;
    float* e1_1    = (float*)(ws + off);    off += (size_t)4 * NN * 4;
    float* e2_1    = (float*)(ws + off);    off += (size_t)4 * NN * 4;
    float* e1_2    = (float*)(ws + off);    off += (size_t)NN * 4;
    float* e2_2    = (float*)(ws + off);    off += (size_t)NN * 4;
    unsigned int* keys = (unsigned int*)(ws + off); off += 256;   // [0..3] l1, [4] l2
    float* pnum    = (float*)(ws + off);    off += (size_t)8 * NN * 128 * 4;         // 16 MB
    float* pden    = (float*)(ws + off);    off += (size_t)8 * NN * 4;               // 128 KB
    // layer-2 partials alias layer-1's (serial stream, disjoint lifetime)
    float* pnum2 = pnum;
    float* pden2 = pden;

    hipMemsetAsync(keys, 0, 32, stream);
    k_bitmask<<<NN / 4, 256, 0, stream>>>(g, bm);
    k_cast<<<(NN * KD / 4 + 255) / 256, 256, 0, stream>>>(inputs, Xbf, NN * KD / 4);
    k_tc<<<dim3(KD / 64, 2, 4), 256, 0, stream>>>(W1, W1T, KD, 128);
    k_tc<<<dim3(KD / 64, 1, 1), 256, 0, stream>>>(W2, W2T, KD, 64);
    // layer 1
    k_gemm_fused<128><<<dim3(NN / 32, 4), 512, 0, stream>>>(Xbf, W1T, a1, WhT1, s1_1, s2_1, keys);
    k_prepE<<<4 * NN / 256, 256, 0, stream>>>(s2_1, keys, e1_1, e2_1);
    k_agg9<128, 16, 4><<<dim3(NN / 128, 4, 2), 1024, 0, stream>>>(
        WhT1, s1_1, e1_1, e2_1, keys, (const unsigned char*)bm, pnum, pden, NN / 128 / 2, 4);
    k_reduce1<<<NN * 128 / 256, 256, 0, stream>>>(pnum, pden, hbuf);
    // layer 2
    k_gemm_fused<64><<<dim3(NN / 32, 1), 512, 0, stream>>>(hbuf, W2T, a2, WhT2, s1_2, s2_2, keys + 4);
    k_prepE<<<NN / 256, 256, 0, stream>>>(s2_2, keys + 4, e1_2, e2_2);
    k_agg9<64, 8, 4><<<dim3(NN / 64, 1, 8), 512, 0, stream>>>(
        WhT2, s1_2, e1_2, e2_2, keys + 4, (const unsigned char*)bm, pnum2, pden2, NN / 128 / 8, 1);
    k_reduce2<<<NN * 16 / 256, 256, 0, stream>>>(pnum2, pden2, out);
}

// Round 10
// 119.958 us; speedup vs baseline: 1.7742x; 1.6512x over previous
//
#include <hip/hip_runtime.h>
#include <hip/hip_bf16.h>
#include <stdint.h>

#define NN 4096      // nodes
#define KD 512       // input dim of both GEMMs (512 = IN_DIM = HID*HEADS)
#define LOG2E 1.4426950408889634f

typedef __attribute__((ext_vector_type(8))) short short8;
typedef __attribute__((ext_vector_type(4))) float f32x4;

__device__ __forceinline__ float lrelu(float x) { return fmaxf(x, 0.2f * x); }

__device__ __forceinline__ unsigned short f2bf(float f) {
    uint32_t u = __float_as_uint(f);
    u += 0x7fff + ((u >> 16) & 1);           // RNE
    return (unsigned short)(u >> 16);
}

// 2^x via hardware transcendental (scores are pre-scaled by log2e)
__device__ __forceinline__ float exp2_fast(float x) {
    float r; asm("v_exp_f32 %0, %1" : "=v"(r) : "v"(x)); return r;
}

// pack 2 f32 -> 2 bf16 (RNE), lo -> [15:0], hi -> [31:16]
__device__ __forceinline__ uint32_t cvt_pk_bf16(float lo, float hi) {
    uint32_t r; asm("v_cvt_pk_bf16_f32 %0, %1, %2" : "=v"(r) : "v"(lo), "v"(hi)); return r;
}

// async global->LDS, 16B per lane; lds ptr must be wave-uniform base
__device__ __forceinline__ void glds16(const void* g, void* l) {
    __builtin_amdgcn_global_load_lds(
        (const __attribute__((address_space(1))) uint32_t*)g,
        (__attribute__((address_space(3))) uint32_t*)l, 16, 0, 0);
}

// ---------------- bitmask: g[N][N] int32 -> bm[N][64] uint64 ----------------
__global__ void k_bitmask(const int* __restrict__ g, uint64_t* __restrict__ bm) {
    int wave = threadIdx.x >> 6;
    int lane = threadIdx.x & 63;
    int row = blockIdx.x * 4 + wave;
    const int* grow = g + (size_t)row * NN;
    #pragma unroll 4
    for (int w = 0; w < 64; ++w) {
        int v = grow[w * 64 + lane];
        unsigned long long m = __ballot(v > 0);
        if (lane == 0) bm[(size_t)row * 64 + w] = m;
    }
}

// ---------------- cast f32 -> bf16 (vectorized) ----------------
__global__ void k_cast(const float* __restrict__ x, unsigned short* __restrict__ y, int n4) {
    int i = blockIdx.x * 256 + threadIdx.x;
    if (i < n4) {
        float4 v = ((const float4*)x)[i];
        uint2 o;
        o.x = (uint32_t)f2bf(v.x) | ((uint32_t)f2bf(v.y) << 16);
        o.y = (uint32_t)f2bf(v.z) | ((uint32_t)f2bf(v.w) << 16);
        ((uint2*)y)[i] = o;
    }
}

// ---------------- generic transpose+cast: src f32 [b][R][C] -> dst bf16 [b][C][R] ----------------
__global__ __launch_bounds__(256)
void k_tc(const float* __restrict__ src, unsigned short* __restrict__ dst, int R, int C) {
    __shared__ float tile[64][65];
    int b = blockIdx.z;
    int r0 = blockIdx.x * 64, c0 = blockIdx.y * 64;
    src += (size_t)b * R * C;
    dst += (size_t)b * C * R;
    int t = threadIdx.x;
    #pragma unroll
    for (int s = 0; s < 16; ++s) {
        int idx = t + s * 256;
        int r = idx >> 6, c = idx & 63;
        tile[r][c] = src[(size_t)(r0 + r) * C + c0 + c];
    }
    __syncthreads();
    #pragma unroll
    for (int s = 0; s < 16; ++s) {
        int idx = t + s * 256;
        int r = idx >> 6, c = idx & 63;
        dst[(size_t)(c0 + r) * R + r0 + c] = f2bf(tile[c][r]);
    }
}

// ---------------- fused MFMA GEMM: Wh = A @ W, epilogue writes FRAGMENT-ORDER tiled WhT ----
// A bf16 [NN][512], WT bf16 [nh][F][512]. BM=32, BK=64, 8 waves (2row x 4col).
// WhT layout: [h][j/128][unit][8] where 16B unit = (fb*256 + jsl*16 + r):
//   feature row = fb*16 + r, j = jtile*128 + jsl*8 .. +8.
// This is EXACTLY the LDS image the aggregation kernel consumes, so its glds16 staging
// source is linear lane-monotonic contiguous 1KB (fully coalesced) and its ds_read is
// R3's frag-order pattern (measured 0 conflicts). s1/s2/smax PRE-SCALED by log2(e).
template <int F>
__global__ __launch_bounds__(512)
void k_gemm_fused(const unsigned short* __restrict__ Abf, const unsigned short* __restrict__ WT,
                  const float* __restrict__ avec,
                  unsigned short* __restrict__ WhT, float* __restrict__ s1g,
                  float* __restrict__ s2g, unsigned int* __restrict__ smaxKey) {
    constexpr int BM = 32, BK = 64;
    constexpr int NCF = F / 64;
    __shared__ unsigned short a_lds[2][BM * BK];
    __shared__ unsigned short b_lds[2][F * BK];
    __shared__ unsigned short t_lds[F * 40];
    __shared__ float sred[BM][2];
    int t = threadIdx.x, lane = t & 63, w = t >> 6;
    int h = blockIdx.y;
    int i0 = blockIdx.x * BM;
    const unsigned short* WTh = WT + (size_t)h * F * KD;
    int r0 = (w >> 2) * 16, c0 = (w & 3) * (F / 4);
    int krow = lane & 15, kgrp = lane >> 4;
    if (t < BM) { sred[t][0] = 0.f; sred[t][1] = 0.f; }
    f32x4 acc[NCF];
    #pragma unroll
    for (int cf = 0; cf < NCF; ++cf) acc[cf] = (f32x4){0.f, 0.f, 0.f, 0.f};

    auto stage = [&](int buf, int kt) {
        int k0 = kt * BK;
        if (w < 4) {            // A tile: 256 chunks
            int c = w * 64 + lane;
            int row = c >> 3, slot = c & 7;
            glds16(Abf + (size_t)(i0 + row) * KD + k0 + ((slot ^ (row & 7)) * 8),
                   &a_lds[buf][(w * 64) * 8]);
        }
        #pragma unroll
        for (int s = 0; s < F / 64; ++s) {   // B tile: 8F chunks
            int c = w * F + s * 64 + lane;
            int row = c >> 3, slot = c & 7;
            glds16(WTh + (size_t)row * KD + k0 + ((slot ^ (row & 7)) * 8),
                   &b_lds[buf][(w * F + s * 64) * 8]);
        }
    };

    stage(0, 0);
    __syncthreads();
    int cur = 0;
    for (int kt = 0; kt < KD / BK; ++kt) {
        int nxt = cur ^ 1;
        if (kt + 1 < KD / BK) stage(nxt, kt + 1);
        #pragma unroll
        for (int ks = 0; ks < 2; ++ks) {
            int koff = ks * 32 + kgrp * 8;
            int arow = r0 + krow;
            short8 av = *(const short8*)((const char*)&a_lds[cur][arow * BK] +
                                         ((koff * 2) ^ ((arow & 7) << 4)));
            #pragma unroll
            for (int cf = 0; cf < NCF; ++cf) {
                int brow = c0 + cf * 16 + krow;
                short8 bv = *(const short8*)((const char*)&b_lds[cur][brow * BK] +
                                             ((koff * 2) ^ ((brow & 7) << 4)));
                acc[cf] = __builtin_amdgcn_mfma_f32_16x16x32_bf16(av, bv, acc[cf], 0, 0, 0);
            }
        }
        __syncthreads();
        cur = nxt;
    }
    // ---- epilogue ----
    // transpose-store acc to t_lds bf16 + score partials
    float p1[4] = {0.f, 0.f, 0.f, 0.f}, p2[4] = {0.f, 0.f, 0.f, 0.f};
    const float* ah = avec + (size_t)h * 2 * F;
    #pragma unroll
    for (int cf = 0; cf < NCF; ++cf) {
        int col = c0 + cf * 16 + krow;
        float aw1 = ah[col], aw2 = ah[F + col];
        #pragma unroll
        for (int r = 0; r < 4; ++r) {
            int row = r0 + kgrp * 4 + r;
            t_lds[col * 40 + row] = f2bf(acc[cf][r]);
            p1[r] += acc[cf][r] * aw1;
            p2[r] += acc[cf][r] * aw2;
        }
    }
    #pragma unroll
    for (int d = 1; d < 16; d <<= 1) {
        #pragma unroll
        for (int r = 0; r < 4; ++r) { p1[r] += __shfl_xor(p1[r], d); p2[r] += __shfl_xor(p2[r], d); }
    }
    if (krow == 0) {
        #pragma unroll
        for (int r = 0; r < 4; ++r) {
            int row = r0 + kgrp * 4 + r;
            atomicAdd(&sred[row][0], p1[r]);
            atomicAdd(&sred[row][1], p2[r]);
        }
    }
    __syncthreads();
    {
        int col = t >> 2, seg = (t & 3) * 8;
        if (col < F) {
            uint4 v = *(const uint4*)&t_lds[col * 40 + seg];
            int jb = i0 >> 7, jl = (i0 & 127) + seg;   // fragment-order tiled store
            int unit = (col >> 4) * 256 + (jl >> 3) * 16 + (col & 15);
            *(uint4*)&WhT[((size_t)h * (NN / 128) + jb) * ((size_t)F * 128) + (size_t)unit * 8] = v;
        }
    }
    if (t < BM) {
        s1g[(size_t)h * NN + i0 + t] = sred[t][0] * LOG2E;
        s2g[(size_t)h * NN + i0 + t] = sred[t][1] * LOG2E;
    }
    if (w == 0) {
        float v = (t < BM) ? sred[t][1] * LOG2E : -3.4e38f;
        #pragma unroll
        for (int d = 1; d < 64; d <<= 1) v = fmaxf(v, __shfl_xor(v, d));
        if (lane == 0) {
            uint32_t b = __float_as_uint(v);
            uint32_t key = (b & 0x80000000u) ? ~b : (b | 0x80000000u);
            atomicMax(smaxKey + h, key);
        }
    }
}

// ---------------- register-P MFMA masked-softmax aggregation (R3 math, frag-tiled src) ----
// NW waves; NJH j-slices; rg = w/NJH owns 32 rows, jh = w%NJH owns K=32 of TJ=128.
// WhT tiles stored in FRAGMENT ORDER: glds16 source is linear lane-monotonic
// (contiguous 1KB per instr -> fully coalesced), LDS unit == global unit, ds_read is
// R3's frag-order pattern (0 conflicts measured). computeP is R3's exp2 form (SD = 10
// regs -- R8/R9's 18-reg SD spilled ~1KB/thread, WRITE 274-356MB). ONE variable vs R3:
// the staging layout. Sync: R3's raw-barrier counted-wait loop; tri-buffer covers WAR.
template <int F, int NW, int NJH>
__global__ __launch_bounds__(NW * 64, 4)
void k_agg10(const unsigned short* __restrict__ WhT, const float* __restrict__ s1v,
             const float* __restrict__ s2v, const unsigned int* __restrict__ smaxKey,
             const unsigned char* __restrict__ bmb,
             float* __restrict__ pnum, float* __restrict__ pden, int njt, int nh) {
    constexpr int TI = (NW / NJH) * 32, TJ = NJH * 32;
    constexpr int NB = F / 16;            // B frags per wave
    constexpr int CPR = TJ / 8;           // mask bytes per tile row
    constexpr int TUNITS = F * (TJ / 8);  // 16B units per tile
    constexpr int CH_W = TUNITS / NW;     // units staged per wave
    constexpr int XF = F + 4;             // padded exchange stride (words)
    constexpr int XROWS = TI / 2;
    constexpr size_t ST_BYTES = sizeof(unsigned short) * 3 * F * TJ;
    constexpr size_t XCH_BYTES = sizeof(float) * (size_t)(NJH - 1) * XROWS * XF;
    constexpr size_t SM_BYTES = ST_BYTES > XCH_BYTES ? ST_BYTES : XCH_BYTES;
    __shared__ __align__(16) char smem[SM_BYTES];
    __shared__ float den_sh[NJH][TI];
    auto whT_lds = (unsigned short (*)[F * TJ])smem;
    float* xch = (float*)smem;
    int t = threadIdx.x, l = t & 63, w = t >> 6;
    int h = blockIdx.y, js = blockIdx.z;
    int i0 = blockIdx.x * TI;
    int rg = w / NJH, jh = w % NJH;
    int r0 = rg * 32;
    const unsigned short* WhTt = WhT + (size_t)h * (NN / 128) * ((size_t)F * 128);
    const float* s2h = s2v + (size_t)h * NN;
    unsigned int kk = smaxKey[h];
    float smax = __uint_as_float((kk & 0x80000000u) ? (kk ^ 0x80000000u) : ~kk);
    int lane16 = l & 15, kgrp = l >> 4;
    int rowA = i0 + r0 + lane16;
    int rowB = rowA + 16;
    float s1A = s1v[(size_t)h * NN + rowA];
    float s1B = s1v[(size_t)h * NN + rowB];
    float miA = lrelu(s1A + smax), miB = lrelu(s1B + smax);
    // fold row constants: t = lrelu(s1+q) - mi = max(q + c1, 0.2q + c2)
    float c1A = s1A - miA, c2A = fmaf(0.2f, s1A, -miA);
    float c1B = s1B - miB, c2B = fmaf(0.2f, s1B, -miB);
    int joff = jh * 32 + kgrp * 8;
    int jsbase = js * njt;
    const unsigned char* bmbA = bmb + (size_t)rowA * 512;
    const unsigned char* bmbB = bmb + (size_t)rowB * 512;

    f32x4 acc[2][NB];
    #pragma unroll
    for (int m = 0; m < 2; ++m)
        #pragma unroll
        for (int b = 0; b < NB; ++b) acc[m][b] = (f32x4){0.f, 0.f, 0.f, 0.f};
    float denA = 0.f, denB = 0.f;

    struct SD { float4 q0, q1; unsigned int mA, mB; };
    struct PA { short8 a, b; };

    auto loadSD = [&](int jt) {
        SD s;
        int j0 = (jsbase + jt) * TJ;
        s.q0 = *(const float4*)&s2h[j0 + joff];
        s.q1 = *(const float4*)&s2h[j0 + joff + 4];
        int wb = (jsbase + jt) * CPR + jh * 4 + kgrp;
        s.mA = bmbA[wb];
        s.mB = bmbB[wb];
        return s;
    };

    auto computeP = [&](const SD& s) {
        float q[8] = {s.q0.x, s.q0.y, s.q0.z, s.q0.w, s.q1.x, s.q1.y, s.q1.z, s.q1.w};
        float pA[8], pB[8];
        #pragma unroll
        for (int u = 0; u < 8; ++u) {
            float tA = fmaxf(q[u] + c1A, fmaf(0.2f, q[u], c2A));
            float vA = ((s.mA >> u) & 1u) ? exp2_fast(tA) : 0.f;
            denA += vA; pA[u] = vA;
            float tB = fmaxf(q[u] + c1B, fmaf(0.2f, q[u], c2B));
            float vB = ((s.mB >> u) & 1u) ? exp2_fast(tB) : 0.f;
            denB += vB; pB[u] = vB;
        }
        union { uint32_t d[4]; short8 v; } ua, ub;
        #pragma unroll
        for (int j = 0; j < 4; ++j) {
            ua.d[j] = cvt_pk_bf16(pA[2 * j], pA[2 * j + 1]);
            ub.d[j] = cvt_pk_bf16(pB[2 * j], pB[2 * j + 1]);
        }
        PA p; p.a = ua.v; p.b = ub.v;
        return p;
    };

    // LINEAR staging: lane l of chunk (w,s) loads global unit c = w*CH_W+s*64+l into
    // LDS unit c. Per instruction: contiguous, lane-monotonic 1KB -> fully coalesced.
    auto stage = [&](int buf, int jt) {
        const unsigned short* base = WhTt + (size_t)(jsbase + jt) * ((size_t)F * 128);
        #pragma unroll
        for (int s = 0; s < CH_W / 64; ++s) {
            int c0u = w * CH_W + s * 64;
            glds16(base + (size_t)(c0u + l) * 8, &whT_lds[buf][c0u * 8]);
        }
    };

    // frag-order read (R3, 0 conflicts): unit = (b*16 + jsl)*16 + r,
    // jsl = jh*4+kgrp, r = lane16 -> 16 lanes read contiguous 256B.
    auto domfma = [&](int buf, const PA& pa) {
        #pragma unroll
        for (int b = 0; b < NB; ++b) {
            int unit = (b * 16 + jh * 4 + kgrp) * 16 + lane16;
            short8 bv = *(const short8*)&whT_lds[buf][unit * 8];
            acc[0][b] = __builtin_amdgcn_mfma_f32_16x16x32_bf16(pa.a, bv, acc[0][b], 0, 0, 0);
            acc[1][b] = __builtin_amdgcn_mfma_f32_16x16x32_bf16(pa.b, bv, acc[1][b], 0, 0, 0);
        }
    };

    // prologue (iter-0's pre-barrier wait covers stage(0))
    SD sd_cur = loadSD(0);
    __builtin_amdgcn_sched_barrier(0);
    stage(0, 0);
    __builtin_amdgcn_sched_barrier(0);
    SD sd_nxt;
    if (njt > 1) sd_nxt = loadSD(1);
    PA pa_cur = computeP(sd_cur);
    int cur = 0, nx1 = 1;
    for (int jt = 0; jt < njt; ++jt) {
        bool more = jt + 1 < njt;
        if (more) stage(nx1, jt + 1);
        __builtin_amdgcn_sched_barrier(0);   // pin: stage glds16 precede newer loads
        SD sd2;
        if (jt + 2 < njt) sd2 = loadSD(jt + 2);
        PA pa_n;
        if (more) pa_n = computeP(sd_nxt);   // waits loadSD(jt+1) -> drains stage(jt)
        __builtin_amdgcn_sched_barrier(0);
        if (!more) asm volatile("s_waitcnt vmcnt(0)" ::: "memory");
        __builtin_amdgcn_s_barrier();        // raw: stage(jt+1) stays in flight
        __builtin_amdgcn_sched_barrier(0);
        domfma(cur, pa_cur);
        pa_cur = pa_n;
        sd_nxt = sd2;
        cur = nx1;
        nx1 = nx1 + 1 == 3 ? 0 : nx1 + 1;
    }

    // den: sum k-groups (lanes sharing l&15)
    denA += __shfl_xor(denA, 16); denA += __shfl_xor(denA, 32);
    denB += __shfl_xor(denB, 16); denB += __shfl_xor(denB, 32);
    if (l < 16) {
        den_sh[jh][r0 + l] = denA;
        den_sh[jh][r0 + 16 + l] = denB;
    }
    __syncthreads();

    // merge jh slices of acc via LDS (two row-passes), write pnum
    float* pnumS = pnum + ((size_t)(js * nh + h) * NN + i0) * F;
    #pragma unroll
    for (int m = 0; m < 2; ++m) {
        if (jh > 0) {
            float* sl = xch + (size_t)(jh - 1) * XROWS * XF;
            #pragma unroll
            for (int b = 0; b < NB; ++b) {
                int col = b * 16 + lane16;
                #pragma unroll
                for (int r = 0; r < 4; ++r)
                    sl[(rg * 16 + kgrp * 4 + r) * XF + col] = acc[m][b][r];
            }
        }
        __syncthreads();
        if (jh == 0) {
            #pragma unroll
            for (int b = 0; b < NB; ++b) {
                int col = b * 16 + lane16;
                #pragma unroll
                for (int r = 0; r < 4; ++r) {
                    int lrow = rg * 16 + kgrp * 4 + r;
                    int row = r0 + m * 16 + kgrp * 4 + r;
                    float v = acc[m][b][r];
                    #pragma unroll
                    for (int sX = 1; sX < NJH; ++sX)
                        v += xch[((size_t)(sX - 1) * XROWS + lrow) * XF + col];
                    pnumS[(size_t)row * F + col] = v;
                }
            }
        }
        __syncthreads();
    }
    if (t < TI) {
        float d = den_sh[0][t];
        #pragma unroll
        for (int sX = 1; sX < NJH; ++sX) d += den_sh[sX][t];
        pden[(size_t)(js * nh + h) * NN + i0 + t] = d;
    }
}

// ---------------- reduce layer-1 partials -> hbuf bf16 (with ELU) ----------------
__global__ void k_reduce1(const float* __restrict__ pnum, const float* __restrict__ pden,
                          unsigned short* __restrict__ hbuf) {
    int idx = blockIdx.x * 256 + threadIdx.x;   // NN*128 float4s
    int i = idx >> 7;
    int c4 = idx & 127;
    int hh = c4 >> 5, f4 = c4 & 31;
    float4 a = *(const float4*)&pnum[((size_t)hh * NN + i) * 128 + f4 * 4];
    float4 b = *(const float4*)&pnum[((size_t)(4 + hh) * NN + i) * 128 + f4 * 4];
    float den = pden[(size_t)hh * NN + i] + pden[(size_t)(4 + hh) * NN + i];
    float inv = 1.f / den;
    float v[4] = {(a.x + b.x) * inv, (a.y + b.y) * inv, (a.z + b.z) * inv, (a.w + b.w) * inv};
    uint2 o;
    unsigned short e[4];
    #pragma unroll
    for (int u = 0; u < 4; ++u) {
        float x = v[u];
        x = x > 0.f ? x : expm1f(x);
        e[u] = f2bf(x);
    }
    o.x = (uint32_t)e[0] | ((uint32_t)e[1] << 16);
    o.y = (uint32_t)e[2] | ((uint32_t)e[3] << 16);
    *(uint2*)&hbuf[(size_t)i * 512 + c4 * 4] = o;
}

// ---------------- reduce layer-2 partials -> out f32 ----------------
__global__ void k_reduce2(const float* __restrict__ pnum, const float* __restrict__ pden,
                          float* __restrict__ out) {
    int idx = blockIdx.x * 256 + threadIdx.x;   // NN*16 float4s
    int i = idx >> 4;
    int f4 = (idx & 15) * 4;
    float4 s = {0.f, 0.f, 0.f, 0.f};
    float den = 0.f;
    #pragma unroll
    for (int js = 0; js < 8; ++js) {
        float4 v = *(const float4*)&pnum[((size_t)js * NN + i) * 64 + f4];
        s.x += v.x; s.y += v.y; s.z += v.z; s.w += v.w;
        den += pden[(size_t)js * NN + i];
    }
    float inv = 1.f / den;
    s.x *= inv; s.y *= inv; s.z *= inv; s.w *= inv;
    *(float4*)&out[(size_t)i * 64 + f4] = s;
}

extern "C" void kernel_launch(void* const* d_in, const int* in_sizes, int n_in,
                              void* d_out, int out_size, void* d_ws, size_t ws_size,
                              hipStream_t stream) {
    const int*   g      = (const int*)d_in[0];
    const float* inputs = (const float*)d_in[1];
    const float* W1     = (const float*)d_in[2];
    const float* a1     = (const float*)d_in[3];
    const float* W2     = (const float*)d_in[4];
    const float* a2     = (const float*)d_in[5];
    float* out = (float*)d_out;
    char* ws = (char*)d_ws;

    size_t off = 0;
    uint64_t* bm   = (uint64_t*)(ws + off); off += (size_t)NN * 64 * 8;              // 2 MB
    unsigned short* Xbf  = (unsigned short*)(ws + off); off += (size_t)NN * KD * 2;  // 4 MB
    unsigned short* W1T  = (unsigned short*)(ws + off); off += (size_t)4 * 128 * KD * 2;
    unsigned short* W2T  = (unsigned short*)(ws + off); off += (size_t)64 * KD * 2;
    unsigned short* WhT1 = (unsigned short*)(ws + off); off += (size_t)4 * 128 * NN * 2; // 4 MB (tiled)
    unsigned short* WhT2 = (unsigned short*)(ws + off); off += (size_t)64 * NN * 2;      // 0.5 MB (tiled)
    unsigned short* hbuf = (unsigned short*)(ws + off); off += (size_t)NN * KD * 2;      // 4 MB
    float* s1_1    = (float*)(ws + off);    off += (size_t)4 * NN * 4;
    float* s2_1    = (float*)(ws + off);    off += (size_t)4 * NN * 4;
    float* s1_2    = (float*)(ws + off);    off += (size_t)NN * 4;
    float* s2_2    = (float*)(ws + off);    off += (size_t)NN * 4;
    unsigned int* keys = (unsigned int*)(ws + off); off += 256;   // [0..3] l1, [4] l2
    float* pnum    = (float*)(ws + off);    off += (size_t)8 * NN * 128 * 4;         // 16 MB
    float* pden    = (float*)(ws + off);    off += (size_t)8 * NN * 4;               // 128 KB
    // layer-2 partials alias layer-1's (serial stream, disjoint lifetime)
    float* pnum2 = pnum;
    float* pden2 = pden;

    hipMemsetAsync(keys, 0, 32, stream);
    k_bitmask<<<NN / 4, 256, 0, stream>>>(g, bm);
    k_cast<<<(NN * KD / 4 + 255) / 256, 256, 0, stream>>>(inputs, Xbf, NN * KD / 4);
    k_tc<<<dim3(KD / 64, 2, 4), 256, 0, stream>>>(W1, W1T, KD, 128);
    k_tc<<<dim3(KD / 64, 1, 1), 256, 0, stream>>>(W2, W2T, KD, 64);
    // layer 1
    k_gemm_fused<128><<<dim3(NN / 32, 4), 512, 0, stream>>>(Xbf, W1T, a1, WhT1, s1_1, s2_1, keys);
    k_agg10<128, 16, 4><<<dim3(NN / 128, 4, 2), 1024, 0, stream>>>(
        WhT1, s1_1, s2_1, keys, (const unsigned char*)bm, pnum, pden, NN / 128 / 2, 4);
    k_reduce1<<<NN * 128 / 256, 256, 0, stream>>>(pnum, pden, hbuf);
    // layer 2
    k_gemm_fused<64><<<dim3(NN / 32, 1), 512, 0, stream>>>(hbuf, W2T, a2, WhT2, s1_2, s2_2, keys + 4);
    k_agg10<64, 8, 4><<<dim3(NN / 64, 1, 8), 512, 0, stream>>>(
        WhT2, s1_2, s2_2, keys + 4, (const unsigned char*)bm, pnum2, pden2, NN / 128 / 8, 1);
    k_reduce2<<<NN * 16 / 256, 256, 0, stream>>>(pnum2, pden2, out);
}

// Round 11
// 110.575 us; speedup vs baseline: 1.9247x; 1.0849x over previous
//
#include <hip/hip_runtime.h>
#include <hip/hip_bf16.h>
#include <stdint.h>

#define NN 4096      // nodes
#define KD 512       // input dim of both GEMMs (512 = IN_DIM = HID*HEADS)
#define LOG2E 1.4426950408889634f

typedef __attribute__((ext_vector_type(8))) short short8;
typedef __attribute__((ext_vector_type(4))) float f32x4;

__device__ __forceinline__ float lrelu(float x) { return fmaxf(x, 0.2f * x); }

__device__ __forceinline__ unsigned short f2bf(float f) {
    uint32_t u = __float_as_uint(f);
    u += 0x7fff + ((u >> 16) & 1);           // RNE
    return (unsigned short)(u >> 16);
}

// 2^x via hardware transcendental (scores are pre-scaled by log2e)
__device__ __forceinline__ float exp2_fast(float x) {
    float r; asm("v_exp_f32 %0, %1" : "=v"(r) : "v"(x)); return r;
}

// pack 2 f32 -> 2 bf16 (RNE), lo -> [15:0], hi -> [31:16]
__device__ __forceinline__ uint32_t cvt_pk_bf16(float lo, float hi) {
    uint32_t r; asm("v_cvt_pk_bf16_f32 %0, %1, %2" : "=v"(r) : "v"(lo), "v"(hi)); return r;
}

// async global->LDS, 16B per lane; lds ptr must be wave-uniform base
__device__ __forceinline__ void glds16(const void* g, void* l) {
    __builtin_amdgcn_global_load_lds(
        (const __attribute__((address_space(1))) uint32_t*)g,
        (__attribute__((address_space(3))) uint32_t*)l, 16, 0, 0);
}

// ---------------- bitmask: g[N][N] int32 -> bit array bm[N][512B] ----------------
// Thread-local bit assembly (no ballot, no serial per-wave chain): thread t builds
// mask BYTE t from 8 consecutive ints (2 x int4 dense loads). Pure streaming
// elementwise kernel -- latency hidden by TLP (the old ballot version ran 64 serial
// load->ballot iterations per wave: 2.2% VALU, 1.5 TB/s effective, 45us).
__global__ void k_bitmask(const int* __restrict__ g, uint64_t* __restrict__ bm) {
    int b = blockIdx.x * 256 + threadIdx.x;       // byte index, 0 .. NN*512
    const int* src = g + (size_t)b * 8;           // 8 ints per byte
    int4 v0 = *(const int4*)src;
    int4 v1 = *(const int4*)(src + 4);
    unsigned int byte =
        (unsigned int)(v0.x > 0)       | ((unsigned int)(v0.y > 0) << 1) |
        ((unsigned int)(v0.z > 0) << 2) | ((unsigned int)(v0.w > 0) << 3) |
        ((unsigned int)(v1.x > 0) << 4) | ((unsigned int)(v1.y > 0) << 5) |
        ((unsigned int)(v1.z > 0) << 6) | ((unsigned int)(v1.w > 0) << 7);
    ((unsigned char*)bm)[b] = (unsigned char)byte;
}

// ---------------- cast f32 -> bf16 (vectorized) ----------------
__global__ void k_cast(const float* __restrict__ x, unsigned short* __restrict__ y, int n4) {
    int i = blockIdx.x * 256 + threadIdx.x;
    if (i < n4) {
        float4 v = ((const float4*)x)[i];
        uint2 o;
        o.x = (uint32_t)f2bf(v.x) | ((uint32_t)f2bf(v.y) << 16);
        o.y = (uint32_t)f2bf(v.z) | ((uint32_t)f2bf(v.w) << 16);
        ((uint2*)y)[i] = o;
    }
}

// ---------------- generic transpose+cast: src f32 [b][R][C] -> dst bf16 [b][C][R] ----------------
__global__ __launch_bounds__(256)
void k_tc(const float* __restrict__ src, unsigned short* __restrict__ dst, int R, int C) {
    __shared__ float tile[64][65];
    int b = blockIdx.z;
    int r0 = blockIdx.x * 64, c0 = blockIdx.y * 64;
    src += (size_t)b * R * C;
    dst += (size_t)b * C * R;
    int t = threadIdx.x;
    #pragma unroll
    for (int s = 0; s < 16; ++s) {
        int idx = t + s * 256;
        int r = idx >> 6, c = idx & 63;
        tile[r][c] = src[(size_t)(r0 + r) * C + c0 + c];
    }
    __syncthreads();
    #pragma unroll
    for (int s = 0; s < 16; ++s) {
        int idx = t + s * 256;
        int r = idx >> 6, c = idx & 63;
        dst[(size_t)(c0 + r) * R + r0 + c] = f2bf(tile[c][r]);
    }
}

// ---------------- fused MFMA GEMM: Wh = A @ W, epilogue writes FRAGMENT-ORDER tiled WhT ----
// A bf16 [NN][512], WT bf16 [nh][F][512]. BM=32, BK=64, 8 waves (2row x 4col).
// WhT layout: [h][j/128][unit][8] where 16B unit = (fb*256 + jsl*16 + r):
//   feature row = fb*16 + r, j = jtile*128 + jsl*8 .. +8.
// This is EXACTLY the LDS image the aggregation kernel consumes, so its glds16 staging
// source is linear lane-monotonic contiguous 1KB (fully coalesced) and its ds_read is
// R3's frag-order pattern (measured 0 conflicts). s1/s2/smax PRE-SCALED by log2(e).
template <int F>
__global__ __launch_bounds__(512)
void k_gemm_fused(const unsigned short* __restrict__ Abf, const unsigned short* __restrict__ WT,
                  const float* __restrict__ avec,
                  unsigned short* __restrict__ WhT, float* __restrict__ s1g,
                  float* __restrict__ s2g, unsigned int* __restrict__ smaxKey) {
    constexpr int BM = 32, BK = 64;
    constexpr int NCF = F / 64;
    __shared__ unsigned short a_lds[2][BM * BK];
    __shared__ unsigned short b_lds[2][F * BK];
    __shared__ unsigned short t_lds[F * 40];
    __shared__ float sred[BM][2];
    int t = threadIdx.x, lane = t & 63, w = t >> 6;
    int h = blockIdx.y;
    int i0 = blockIdx.x * BM;
    const unsigned short* WTh = WT + (size_t)h * F * KD;
    int r0 = (w >> 2) * 16, c0 = (w & 3) * (F / 4);
    int krow = lane & 15, kgrp = lane >> 4;
    if (t < BM) { sred[t][0] = 0.f; sred[t][1] = 0.f; }
    f32x4 acc[NCF];
    #pragma unroll
    for (int cf = 0; cf < NCF; ++cf) acc[cf] = (f32x4){0.f, 0.f, 0.f, 0.f};

    auto stage = [&](int buf, int kt) {
        int k0 = kt * BK;
        if (w < 4) {            // A tile: 256 chunks
            int c = w * 64 + lane;
            int row = c >> 3, slot = c & 7;
            glds16(Abf + (size_t)(i0 + row) * KD + k0 + ((slot ^ (row & 7)) * 8),
                   &a_lds[buf][(w * 64) * 8]);
        }
        #pragma unroll
        for (int s = 0; s < F / 64; ++s) {   // B tile: 8F chunks
            int c = w * F + s * 64 + lane;
            int row = c >> 3, slot = c & 7;
            glds16(WTh + (size_t)row * KD + k0 + ((slot ^ (row & 7)) * 8),
                   &b_lds[buf][(w * F + s * 64) * 8]);
        }
    };

    stage(0, 0);
    __syncthreads();
    int cur = 0;
    for (int kt = 0; kt < KD / BK; ++kt) {
        int nxt = cur ^ 1;
        if (kt + 1 < KD / BK) stage(nxt, kt + 1);
        #pragma unroll
        for (int ks = 0; ks < 2; ++ks) {
            int koff = ks * 32 + kgrp * 8;
            int arow = r0 + krow;
            short8 av = *(const short8*)((const char*)&a_lds[cur][arow * BK] +
                                         ((koff * 2) ^ ((arow & 7) << 4)));
            #pragma unroll
            for (int cf = 0; cf < NCF; ++cf) {
                int brow = c0 + cf * 16 + krow;
                short8 bv = *(const short8*)((const char*)&b_lds[cur][brow * BK] +
                                             ((koff * 2) ^ ((brow & 7) << 4)));
                acc[cf] = __builtin_amdgcn_mfma_f32_16x16x32_bf16(av, bv, acc[cf], 0, 0, 0);
            }
        }
        __syncthreads();
        cur = nxt;
    }
    // ---- epilogue ----
    // transpose-store acc to t_lds bf16 + score partials
    float p1[4] = {0.f, 0.f, 0.f, 0.f}, p2[4] = {0.f, 0.f, 0.f, 0.f};
    const float* ah = avec + (size_t)h * 2 * F;
    #pragma unroll
    for (int cf = 0; cf < NCF; ++cf) {
        int col = c0 + cf * 16 + krow;
        float aw1 = ah[col], aw2 = ah[F + col];
        #pragma unroll
        for (int r = 0; r < 4; ++r) {
            int row = r0 + kgrp * 4 + r;
            t_lds[col * 40 + row] = f2bf(acc[cf][r]);
            p1[r] += acc[cf][r] * aw1;
            p2[r] += acc[cf][r] * aw2;
        }
    }
    #pragma unroll
    for (int d = 1; d < 16; d <<= 1) {
        #pragma unroll
        for (int r = 0; r < 4; ++r) { p1[r] += __shfl_xor(p1[r], d); p2[r] += __shfl_xor(p2[r], d); }
    }
    if (krow == 0) {
        #pragma unroll
        for (int r = 0; r < 4; ++r) {
            int row = r0 + kgrp * 4 + r;
            atomicAdd(&sred[row][0], p1[r]);
            atomicAdd(&sred[row][1], p2[r]);
        }
    }
    __syncthreads();
    {
        int col = t >> 2, seg = (t & 3) * 8;
        if (col < F) {
            uint4 v = *(const uint4*)&t_lds[col * 40 + seg];
            int jb = i0 >> 7, jl = (i0 & 127) + seg;   // fragment-order tiled store
            int unit = (col >> 4) * 256 + (jl >> 3) * 16 + (col & 15);
            *(uint4*)&WhT[((size_t)h * (NN / 128) + jb) * ((size_t)F * 128) + (size_t)unit * 8] = v;
        }
    }
    if (t < BM) {
        s1g[(size_t)h * NN + i0 + t] = sred[t][0] * LOG2E;
        s2g[(size_t)h * NN + i0 + t] = sred[t][1] * LOG2E;
    }
    if (w == 0) {
        float v = (t < BM) ? sred[t][1] * LOG2E : -3.4e38f;
        #pragma unroll
        for (int d = 1; d < 64; d <<= 1) v = fmaxf(v, __shfl_xor(v, d));
        if (lane == 0) {
            uint32_t b = __float_as_uint(v);
            uint32_t key = (b & 0x80000000u) ? ~b : (b | 0x80000000u);
            atomicMax(smaxKey + h, key);
        }
    }
}

// ---------------- register-P MFMA masked-softmax aggregation (R3 math, frag-tiled src) ----
// NW waves; NJH j-slices; rg = w/NJH owns 32 rows, jh = w%NJH owns K=32 of TJ=128.
// WhT tiles stored in FRAGMENT ORDER: glds16 source is linear lane-monotonic
// (contiguous 1KB per instr -> fully coalesced), LDS unit == global unit, ds_read is
// R3's frag-order pattern (0 conflicts measured). computeP is R3's exp2 form (SD = 10
// regs). Sync: R3's raw-barrier counted-wait loop; tri-buffer covers WAR.
template <int F, int NW, int NJH>
__global__ __launch_bounds__(NW * 64, 4)
void k_agg10(const unsigned short* __restrict__ WhT, const float* __restrict__ s1v,
             const float* __restrict__ s2v, const unsigned int* __restrict__ smaxKey,
             const unsigned char* __restrict__ bmb,
             float* __restrict__ pnum, float* __restrict__ pden, int njt, int nh) {
    constexpr int TI = (NW / NJH) * 32, TJ = NJH * 32;
    constexpr int NB = F / 16;            // B frags per wave
    constexpr int CPR = TJ / 8;           // mask bytes per tile row
    constexpr int TUNITS = F * (TJ / 8);  // 16B units per tile
    constexpr int CH_W = TUNITS / NW;     // units staged per wave
    constexpr int XF = F + 4;             // padded exchange stride (words)
    constexpr int XROWS = TI / 2;
    constexpr size_t ST_BYTES = sizeof(unsigned short) * 3 * F * TJ;
    constexpr size_t XCH_BYTES = sizeof(float) * (size_t)(NJH - 1) * XROWS * XF;
    constexpr size_t SM_BYTES = ST_BYTES > XCH_BYTES ? ST_BYTES : XCH_BYTES;
    __shared__ __align__(16) char smem[SM_BYTES];
    __shared__ float den_sh[NJH][TI];
    auto whT_lds = (unsigned short (*)[F * TJ])smem;
    float* xch = (float*)smem;
    int t = threadIdx.x, l = t & 63, w = t >> 6;
    int h = blockIdx.y, js = blockIdx.z;
    int i0 = blockIdx.x * TI;
    int rg = w / NJH, jh = w % NJH;
    int r0 = rg * 32;
    const unsigned short* WhTt = WhT + (size_t)h * (NN / 128) * ((size_t)F * 128);
    const float* s2h = s2v + (size_t)h * NN;
    unsigned int kk = smaxKey[h];
    float smax = __uint_as_float((kk & 0x80000000u) ? (kk ^ 0x80000000u) : ~kk);
    int lane16 = l & 15, kgrp = l >> 4;
    int rowA = i0 + r0 + lane16;
    int rowB = rowA + 16;
    float s1A = s1v[(size_t)h * NN + rowA];
    float s1B = s1v[(size_t)h * NN + rowB];
    float miA = lrelu(s1A + smax), miB = lrelu(s1B + smax);
    // fold row constants: t = lrelu(s1+q) - mi = max(q + c1, 0.2q + c2)
    float c1A = s1A - miA, c2A = fmaf(0.2f, s1A, -miA);
    float c1B = s1B - miB, c2B = fmaf(0.2f, s1B, -miB);
    int joff = jh * 32 + kgrp * 8;
    int jsbase = js * njt;
    const unsigned char* bmbA = bmb + (size_t)rowA * 512;
    const unsigned char* bmbB = bmb + (size_t)rowB * 512;

    f32x4 acc[2][NB];
    #pragma unroll
    for (int m = 0; m < 2; ++m)
        #pragma unroll
        for (int b = 0; b < NB; ++b) acc[m][b] = (f32x4){0.f, 0.f, 0.f, 0.f};
    float denA = 0.f, denB = 0.f;

    struct SD { float4 q0, q1; unsigned int mA, mB; };
    struct PA { short8 a, b; };

    auto loadSD = [&](int jt) {
        SD s;
        int j0 = (jsbase + jt) * TJ;
        s.q0 = *(const float4*)&s2h[j0 + joff];
        s.q1 = *(const float4*)&s2h[j0 + joff + 4];
        int wb = (jsbase + jt) * CPR + jh * 4 + kgrp;
        s.mA = bmbA[wb];
        s.mB = bmbB[wb];
        return s;
    };

    auto computeP = [&](const SD& s) {
        float q[8] = {s.q0.x, s.q0.y, s.q0.z, s.q0.w, s.q1.x, s.q1.y, s.q1.z, s.q1.w};
        float pA[8], pB[8];
        #pragma unroll
        for (int u = 0; u < 8; ++u) {
            float tA = fmaxf(q[u] + c1A, fmaf(0.2f, q[u], c2A));
            float vA = ((s.mA >> u) & 1u) ? exp2_fast(tA) : 0.f;
            denA += vA; pA[u] = vA;
            float tB = fmaxf(q[u] + c1B, fmaf(0.2f, q[u], c2B));
            float vB = ((s.mB >> u) & 1u) ? exp2_fast(tB) : 0.f;
            denB += vB; pB[u] = vB;
        }
        union { uint32_t d[4]; short8 v; } ua, ub;
        #pragma unroll
        for (int j = 0; j < 4; ++j) {
            ua.d[j] = cvt_pk_bf16(pA[2 * j], pA[2 * j + 1]);
            ub.d[j] = cvt_pk_bf16(pB[2 * j], pB[2 * j + 1]);
        }
        PA p; p.a = ua.v; p.b = ub.v;
        return p;
    };

    // LINEAR staging: lane l of chunk (w,s) loads global unit c = w*CH_W+s*64+l into
    // LDS unit c. Per instruction: contiguous, lane-monotonic 1KB -> fully coalesced.
    auto stage = [&](int buf, int jt) {
        const unsigned short* base = WhTt + (size_t)(jsbase + jt) * ((size_t)F * 128);
        #pragma unroll
        for (int s = 0; s < CH_W / 64; ++s) {
            int c0u = w * CH_W + s * 64;
            glds16(base + (size_t)(c0u + l) * 8, &whT_lds[buf][c0u * 8]);
        }
    };

    // frag-order read (R3, 0 conflicts): unit = (b*16 + jsl)*16 + r,
    // jsl = jh*4+kgrp, r = lane16 -> 16 lanes read contiguous 256B.
    auto domfma = [&](int buf, const PA& pa) {
        #pragma unroll
        for (int b = 0; b < NB; ++b) {
            int unit = (b * 16 + jh * 4 + kgrp) * 16 + lane16;
            short8 bv = *(const short8*)&whT_lds[buf][unit * 8];
            acc[0][b] = __builtin_amdgcn_mfma_f32_16x16x32_bf16(pa.a, bv, acc[0][b], 0, 0, 0);
            acc[1][b] = __builtin_amdgcn_mfma_f32_16x16x32_bf16(pa.b, bv, acc[1][b], 0, 0, 0);
        }
    };

    // prologue (iter-0's pre-barrier wait covers stage(0))
    SD sd_cur = loadSD(0);
    __builtin_amdgcn_sched_barrier(0);
    stage(0, 0);
    __builtin_amdgcn_sched_barrier(0);
    SD sd_nxt;
    if (njt > 1) sd_nxt = loadSD(1);
    PA pa_cur = computeP(sd_cur);
    int cur = 0, nx1 = 1;
    for (int jt = 0; jt < njt; ++jt) {
        bool more = jt + 1 < njt;
        if (more) stage(nx1, jt + 1);
        __builtin_amdgcn_sched_barrier(0);   // pin: stage glds16 precede newer loads
        SD sd2;
        if (jt + 2 < njt) sd2 = loadSD(jt + 2);
        PA pa_n;
        if (more) pa_n = computeP(sd_nxt);   // waits loadSD(jt+1) -> drains stage(jt)
        __builtin_amdgcn_sched_barrier(0);
        if (!more) asm volatile("s_waitcnt vmcnt(0)" ::: "memory");
        __builtin_amdgcn_s_barrier();        // raw: stage(jt+1) stays in flight
        __builtin_amdgcn_sched_barrier(0);
        domfma(cur, pa_cur);
        pa_cur = pa_n;
        sd_nxt = sd2;
        cur = nx1;
        nx1 = nx1 + 1 == 3 ? 0 : nx1 + 1;
    }

    // den: sum k-groups (lanes sharing l&15)
    denA += __shfl_xor(denA, 16); denA += __shfl_xor(denA, 32);
    denB += __shfl_xor(denB, 16); denB += __shfl_xor(denB, 32);
    if (l < 16) {
        den_sh[jh][r0 + l] = denA;
        den_sh[jh][r0 + 16 + l] = denB;
    }
    __syncthreads();

    // merge jh slices of acc via LDS (two row-passes), write pnum
    float* pnumS = pnum + ((size_t)(js * nh + h) * NN + i0) * F;
    #pragma unroll
    for (int m = 0; m < 2; ++m) {
        if (jh > 0) {
            float* sl = xch + (size_t)(jh - 1) * XROWS * XF;
            #pragma unroll
            for (int b = 0; b < NB; ++b) {
                int col = b * 16 + lane16;
                #pragma unroll
                for (int r = 0; r < 4; ++r)
                    sl[(rg * 16 + kgrp * 4 + r) * XF + col] = acc[m][b][r];
            }
        }
        __syncthreads();
        if (jh == 0) {
            #pragma unroll
            for (int b = 0; b < NB; ++b) {
                int col = b * 16 + lane16;
                #pragma unroll
                for (int r = 0; r < 4; ++r) {
                    int lrow = rg * 16 + kgrp * 4 + r;
                    int row = r0 + m * 16 + kgrp * 4 + r;
                    float v = acc[m][b][r];
                    #pragma unroll
                    for (int sX = 1; sX < NJH; ++sX)
                        v += xch[((size_t)(sX - 1) * XROWS + lrow) * XF + col];
                    pnumS[(size_t)row * F + col] = v;
                }
            }
        }
        __syncthreads();
    }
    if (t < TI) {
        float d = den_sh[0][t];
        #pragma unroll
        for (int sX = 1; sX < NJH; ++sX) d += den_sh[sX][t];
        pden[(size_t)(js * nh + h) * NN + i0 + t] = d;
    }
}

// ---------------- reduce layer-1 partials -> hbuf bf16 (with ELU) ----------------
__global__ void k_reduce1(const float* __restrict__ pnum, const float* __restrict__ pden,
                          unsigned short* __restrict__ hbuf) {
    int idx = blockIdx.x * 256 + threadIdx.x;   // NN*128 float4s
    int i = idx >> 7;
    int c4 = idx & 127;
    int hh = c4 >> 5, f4 = c4 & 31;
    float4 a = *(const float4*)&pnum[((size_t)hh * NN + i) * 128 + f4 * 4];
    float4 b = *(const float4*)&pnum[((size_t)(4 + hh) * NN + i) * 128 + f4 * 4];
    float den = pden[(size_t)hh * NN + i] + pden[(size_t)(4 + hh) * NN + i];
    float inv = 1.f / den;
    float v[4] = {(a.x + b.x) * inv, (a.y + b.y) * inv, (a.z + b.z) * inv, (a.w + b.w) * inv};
    uint2 o;
    unsigned short e[4];
    #pragma unroll
    for (int u = 0; u < 4; ++u) {
        float x = v[u];
        x = x > 0.f ? x : expm1f(x);
        e[u] = f2bf(x);
    }
    o.x = (uint32_t)e[0] | ((uint32_t)e[1] << 16);
    o.y = (uint32_t)e[2] | ((uint32_t)e[3] << 16);
    *(uint2*)&hbuf[(size_t)i * 512 + c4 * 4] = o;
}

// ---------------- reduce layer-2 partials -> out f32 ----------------
__global__ void k_reduce2(const float* __restrict__ pnum, const float* __restrict__ pden,
                          float* __restrict__ out) {
    int idx = blockIdx.x * 256 + threadIdx.x;   // NN*16 float4s
    int i = idx >> 4;
    int f4 = (idx & 15) * 4;
    float4 s = {0.f, 0.f, 0.f, 0.f};
    float den = 0.f;
    #pragma unroll
    for (int js = 0; js < 8; ++js) {
        float4 v = *(const float4*)&pnum[((size_t)js * NN + i) * 64 + f4];
        s.x += v.x; s.y += v.y; s.z += v.z; s.w += v.w;
        den += pden[(size_t)js * NN + i];
    }
    float inv = 1.f / den;
    s.x *= inv; s.y *= inv; s.z *= inv; s.w *= inv;
    *(float4*)&out[(size_t)i * 64 + f4] = s;
}

extern "C" void kernel_launch(void* const* d_in, const int* in_sizes, int n_in,
                              void* d_out, int out_size, void* d_ws, size_t ws_size,
                              hipStream_t stream) {
    const int*   g      = (const int*)d_in[0];
    const float* inputs = (const float*)d_in[1];
    const float* W1     = (const float*)d_in[2];
    const float* a1     = (const float*)d_in[3];
    const float* W2     = (const float*)d_in[4];
    const float* a2     = (const float*)d_in[5];
    float* out = (float*)d_out;
    char* ws = (char*)d_ws;

    size_t off = 0;
    uint64_t* bm   = (uint64_t*)(ws + off); off += (size_t)NN * 64 * 8;              // 2 MB
    unsigned short* Xbf  = (unsigned short*)(ws + off); off += (size_t)NN * KD * 2;  // 4 MB
    unsigned short* W1T  = (unsigned short*)(ws + off); off += (size_t)4 * 128 * KD * 2;
    unsigned short* W2T  = (unsigned short*)(ws + off); off += (size_t)64 * KD * 2;
    unsigned short* WhT1 = (unsigned short*)(ws + off); off += (size_t)4 * 128 * NN * 2; // 4 MB (tiled)
    unsigned short* WhT2 = (unsigned short*)(ws + off); off += (size_t)64 * NN * 2;      // 0.5 MB (tiled)
    unsigned short* hbuf = (unsigned short*)(ws + off); off += (size_t)NN * KD * 2;      // 4 MB
    float* s1_1    = (float*)(ws + off);    off += (size_t)4 * NN * 4;
    float* s2_1    = (float*)(ws + off);    off += (size_t)4 * NN * 4;
    float* s1_2    = (float*)(ws + off);    off += (size_t)NN * 4;
    float* s2_2    = (float*)(ws + off);    off += (size_t)NN * 4;
    unsigned int* keys = (unsigned int*)(ws + off); off += 256;   // [0..3] l1, [4] l2
    float* pnum    = (float*)(ws + off);    off += (size_t)8 * NN * 128 * 4;         // 16 MB
    float* pden    = (float*)(ws + off);    off += (size_t)8 * NN * 4;               // 128 KB
    // layer-2 partials alias layer-1's (serial stream, disjoint lifetime)
    float* pnum2 = pnum;
    float* pden2 = pden;

    hipMemsetAsync(keys, 0, 32, stream);
    k_bitmask<<<NN * 512 / 256, 256, 0, stream>>>(g, bm);
    k_cast<<<(NN * KD / 4 + 255) / 256, 256, 0, stream>>>(inputs, Xbf, NN * KD / 4);
    k_tc<<<dim3(KD / 64, 2, 4), 256, 0, stream>>>(W1, W1T, KD, 128);
    k_tc<<<dim3(KD / 64, 1, 1), 256, 0, stream>>>(W2, W2T, KD, 64);
    // layer 1
    k_gemm_fused<128><<<dim3(NN / 32, 4), 512, 0, stream>>>(Xbf, W1T, a1, WhT1, s1_1, s2_1, keys);
    k_agg10<128, 16, 4><<<dim3(NN / 128, 4, 2), 1024, 0, stream>>>(
        WhT1, s1_1, s2_1, keys, (const unsigned char*)bm, pnum, pden, NN / 128 / 2, 4);
    k_reduce1<<<NN * 128 / 256, 256, 0, stream>>>(pnum, pden, hbuf);
    // layer 2
    k_gemm_fused<64><<<dim3(NN / 32, 1), 512, 0, stream>>>(hbuf, W2T, a2, WhT2, s1_2, s2_2, keys + 4);
    k_agg10<64, 8, 4><<<dim3(NN / 64, 1, 8), 512, 0, stream>>>(
        WhT2, s1_2, s2_2, keys + 4, (const unsigned char*)bm, pnum2, pden2, NN / 128 / 8, 1);
    k_reduce2<<<NN * 16 / 256, 256, 0, stream>>>(pnum2, pden2, out);
}